// Round 8
// baseline (95076.062 us; speedup 1.0000x reference)
//
#include <hip/hip_runtime.h>
#include <hip/hip_bf16.h>

#define S_ 512
#define B_ 128
#define D_ 128
#define H_ 512
#define NB_ 256

// ---- packed f16 2-plane weight layout: 32 slabs x 316 chunks x 1024 shorts ----
#define SLAB_SHORTS 323584
#define PK_TOT 10354688
#define APLANE 65536
#define ASZ    131072  // 2*APLANE

#define SC1F 4.8828125e-4f          // 2^-11
#define SC2F 2.384185791015625e-7f  // 2^-22

typedef short bf16x8 __attribute__((ext_vector_type(8)));
typedef _Float16 f16x8 __attribute__((ext_vector_type(8)));
typedef int i32x4 __attribute__((ext_vector_type(4)));
typedef float f32x4 __attribute__((ext_vector_type(4)));

__device__ __forceinline__ float sigf(float x) { return 1.0f / (1.0f + expf(-x)); }

// plain cached 16B load
__device__ __forceinline__ i32x4 ldg(const short* p) {
  i32x4 o;
  asm volatile("global_load_dwordx4 %0, %1, off" : "=v"(o) : "v"(p));
  return o;
}
#define VMDRAIN()                                    \
  do {                                               \
    asm volatile("s_waitcnt vmcnt(0)" ::: "memory"); \
    __builtin_amdgcn_sched_barrier(0);               \
  } while (0)

// sc1 write-through stores (agent-visible after vmcnt(0); no dirty L2)
__device__ __forceinline__ void stg16s(short* p, unsigned int v) {
  asm volatile("global_store_short %0, %1, off sc1" ::"v"(p), "v"(v) : "memory");
}
__device__ __forceinline__ void stgf_sc(float* p, float v) {
  asm volatile("global_store_dword %0, %1, off sc1" ::"v"(p), "v"(v) : "memory");
}
// f16 2-plane split-store (sc1) / cached gather
__device__ __forceinline__ void st2sc(short* buf, int idx, float v) {
  _Float16 h0 = (_Float16)v;
  _Float16 h1 = (_Float16)((v - (float)h0) * 2048.0f);
  stg16s(buf + idx, (unsigned int)__builtin_bit_cast(unsigned short, h0));
  stg16s(buf + idx + APLANE, (unsigned int)__builtin_bit_cast(unsigned short, h1));
}
__device__ __forceinline__ float ld2p(const short* buf, int idx) {
  float a = (float)__builtin_bit_cast(_Float16, buf[idx]);
  float b = (float)__builtin_bit_cast(_Float16, buf[idx + APLANE]);
  return a + b * SC1F;
}

#define MFMAH(a, b, c) __builtin_amdgcn_mfma_f32_16x16x32_f16(a, b, c, 0, 0, 0)
#define BC16(x) __builtin_bit_cast(f16x8, x)

struct Acc3 {
  f32x4 c0, c1, c2;
};
__device__ __forceinline__ void mac4(Acc3& A, const f16x8& a0, const f16x8& a1,
                                     const f16x8& w0, const f16x8& w1) {
  A.c0 = MFMAH(a0, w0, A.c0);
  A.c1 = MFMAH(a0, w1, A.c1);
  A.c1 = MFMAH(a1, w0, A.c1);
  A.c2 = MFMAH(a1, w1, A.c2);
}
__device__ __forceinline__ f32x4 fin3(const Acc3& A) {
  f32x4 o;
#pragma unroll
  for (int e = 0; e < 4; ++e) o[e] = A.c0[e] + SC1F * A.c1[e] + SC2F * A.c2[e];
  return o;
}

// GEMV unit: weights from LDS (chunk layout: 2KB/chunk, plane@+1KB, lane@lo2),
// activations (2-plane f16, cached global) for TWO m-tiles.
__device__ __forceinline__ void unitL(Acc3& A, Acc3& B, const short* a0,
                                      const short* a1, int ldsBase, int nks, int lo2) {
  extern __shared__ char smem[];
  for (int q = 0; q < nks; q += 4) {
    i32x4 p0[4], p1[4], q0[4], q1[4];
#pragma unroll
    for (int u = 0; u < 4; ++u) {
      p0[u] = ldg(a0 + (q + u) * 32);
      p1[u] = ldg(a0 + (q + u) * 32 + APLANE);
      q0[u] = ldg(a1 + (q + u) * 32);
      q1[u] = ldg(a1 + (q + u) * 32 + APLANE);
    }
    bf16x8 W0[4], W1[4];
#pragma unroll
    for (int u = 0; u < 4; ++u) {
      const char* wb = smem + ldsBase + (size_t)(q + u) * 2048 + lo2;
      W0[u] = *(const bf16x8*)wb;
      W1[u] = *(const bf16x8*)(wb + 1024);
    }
    VMDRAIN();
#pragma unroll
    for (int u = 0; u < 4; ++u) {
      mac4(A, BC16(p0[u]), BC16(p1[u]), BC16(W0[u]), BC16(W1[u]));
      mac4(B, BC16(q0[u]), BC16(q1[u]), BC16(W0[u]), BC16(W1[u]));
    }
  }
}

// x-part: 4 chunks of fp32 x, split on the fly; W from LDS
__device__ __forceinline__ void unitLx(Acc3& A, Acc3& B, const float* xA,
                                       const float* xB, int ldsBase, int lo2) {
  extern __shared__ char smem[];
  f16x8 a0A[4], a1A[4], a0B[4], a1B[4];
#pragma unroll
  for (int u = 0; u < 4; ++u)
#pragma unroll
    for (int e = 0; e < 8; ++e) {
      float v = xA[u * 32 + e];
      _Float16 h0 = (_Float16)v;
      a0A[u][e] = h0;
      a1A[u][e] = (_Float16)((v - (float)h0) * 2048.0f);
      float v2 = xB[u * 32 + e];
      _Float16 g0 = (_Float16)v2;
      a0B[u][e] = g0;
      a1B[u][e] = (_Float16)((v2 - (float)g0) * 2048.0f);
    }
#pragma unroll
  for (int u = 0; u < 4; ++u) {
    const char* wb = smem + ldsBase + (size_t)u * 2048 + lo2;
    bf16x8 W0 = *(const bf16x8*)wb;
    bf16x8 W1 = *(const bf16x8*)(wb + 1024);
    mac4(A, a0A[u], a1A[u], BC16(W0), BC16(W1));
    mac4(B, a0B[u], a1B[u], BC16(W0), BC16(W1));
  }
}

// ---- atomics (agent scope, relaxed, monotonic) ----
__device__ __forceinline__ unsigned int afa(unsigned int* p) {
  return __hip_atomic_fetch_add(p, 1u, __ATOMIC_RELAXED, __HIP_MEMORY_SCOPE_AGENT);
}
__device__ __forceinline__ unsigned int ald(const unsigned int* p) {
  return __hip_atomic_load(p, __ATOMIC_RELAXED, __HIP_MEMORY_SCOPE_AGENT);
}

// full-grid barrier: grouped monotonic atomics; then L1+L2 invalidate (weights in LDS
// are immune; only activations/x refetch). Release = per-wave vmcnt(0) on sc1 stores.
__device__ __forceinline__ void gbar(unsigned int* ctl, unsigned int t, int grp) {
  asm volatile("s_waitcnt vmcnt(0) lgkmcnt(0)" ::: "memory");
  __syncthreads();
  if (threadIdx.x == 0) {
    unsigned int a = afa(&ctl[grp * 32]);
    if (a == t * 32u - 1u) {
      unsigned int m = afa(&ctl[256]);
      if (m == t * 8u - 1u)
        __hip_atomic_store(&ctl[288], t, __ATOMIC_RELAXED, __HIP_MEMORY_SCOPE_AGENT);
    }
    while (ald(&ctl[288]) < t) __builtin_amdgcn_s_sleep(2);
  }
  __syncthreads();
  asm volatile("buffer_inv sc1" ::: "memory");
  __builtin_amdgcn_sched_barrier(0);
}

struct PP {
  const float* x;
  const short* pw;
  short* h0s;
  short* h1s;
  short* xn0;
  short* hn0;
  short* ch0;
  short* xn1;
  short* hn1;
  short* ch1;
  short* o0;
  short* o1;
  const float* bhi0;
  const float* bcho0;
  const float* bhi1;
  const float* bcho1;
  float* out;
  unsigned int* ctl;
};

// Roles (gr = bid>>5): 0 L0-gates | 1 L1-gates | 2 L0 xn/hn | 3 L1 xn/hn
//                      4 B-L0 | 5 B-L1 | 6 C-L0 | 7 C-L1.  Slab s = bid&31.
// Piece chunk counts: {40,64,20,32,48,48,32,32}.
__global__ __launch_bounds__(512, 1) void eltm_p(PP p) {
  extern __shared__ char smem[];
  float* ldsF = (float*)(smem + 131072);  // 8KB combine scratch
  const int tid = threadIdx.x;
  const int lane = tid & 63;
  const int w = tid >> 6;
  const int r = lane & 15;
  const int g = lane >> 4;
  const int bid = blockIdx.x;
  const int s = bid & 31;
  const int gr = bid >> 5;
  const int p2 = w & 3;   // m-tile pair: rows [p2*32, p2*32+32)
  const int hh = w >> 2;  // half-split within role
  const int m0A = p2 * 32;
  const int m0B = p2 * 32 + 16;
  const int lo2 = r * 64 + g * 16;  // byte offset within 1KB plane
  const int n = s * 16 + r;
  const int grp = bid & 7;
  const Acc3 Z = {{0.f, 0.f, 0.f, 0.f}, {0.f, 0.f, 0.f, 0.f}, {0.f, 0.f, 0.f, 0.f}};

  // ---- one-time weight staging: this block's piece -> LDS (linear) ----
  {
    const int preC[9] = {0, 40, 104, 124, 156, 204, 252, 284, 316};
    const int pc = preC[gr + 1] - preC[gr];
    const short* src = p.pw + (size_t)s * SLAB_SHORTS + (size_t)preC[gr] * 1024;
    const int n16 = pc * 128;  // 16B units
    for (int c = tid; c < n16; c += 512)
      *(bf16x8*)(smem + (size_t)c * 16) = *(const bf16x8*)(src + (size_t)c * 8);
  }
  __syncthreads();

  const int aoffA = (m0A + r) * H_ + g * 8;
  const int aoffB = (m0B + r) * H_ + g * 8;

  unsigned int bt = 0;
  for (int i = 0; i <= S_; ++i) {
    const int do0 = i < S_;
    const int do1 = i >= 1;
    const float* xrA = p.x + ((size_t)i * B_ + m0A + r) * D_ + g * 8;
    const float* xrB = p.x + ((size_t)i * B_ + m0B + r) * D_ + g * 8;

    // ================= phase A =================
    if (gr == 0) {
      if (do0) {  // L0 gates -> ch0[step i]
        Acc3 aA = Z, aB = Z;
        if (hh == 0) {  // ig
          unitLx(aA, aB, xrA, xrB, 0, lo2);
          unitL(aA, aB, p.h0s + aoffA, p.h0s + aoffB, 4 * 2048, 16, lo2);
        } else {  // hg
          unitLx(aA, aB, xrA, xrB, 20 * 2048, lo2);
          unitL(aA, aB, p.h0s + aoffA, p.h0s + aoffB, 24 * 2048, 16, lo2);
        }
        f32x4 fA = fin3(aA), fB = fin3(aB);
        if (hh == 1) {
#pragma unroll
          for (int e = 0; e < 4; ++e) {
            ldsF[p2 * 512 + (g * 4 + e) * 16 + r] = fA[e];
            ldsF[p2 * 512 + 256 + (g * 4 + e) * 16 + r] = fB[e];
          }
        }
        __syncthreads();
        if (hh == 0) {
          const float bi = p.bhi0[n], bh = p.bhi0[512 + n];
#pragma unroll
          for (int e = 0; e < 4; ++e) {
            float hgA = ldsF[p2 * 512 + (g * 4 + e) * 16 + r];
            float hgB = ldsF[p2 * 512 + 256 + (g * 4 + e) * 16 + r];
            st2sc(p.ch0, (m0A + g * 4 + e) * H_ + n, sigf(fA[e] + bi) * tanhf(hgA + bh));
            st2sc(p.ch0, (m0B + g * 4 + e) * H_ + n, sigf(fB[e] + bi) * tanhf(hgB + bh));
          }
        }
      }
    } else if (gr == 1) {
      if (do1) {  // L1 gates -> ch1[step i-1]
        Acc3 aA = Z, aB = Z;
        if (hh == 0) {
          unitL(aA, aB, p.h0s + aoffA, p.h0s + aoffB, 0, 16, lo2);
          unitL(aA, aB, p.h1s + aoffA, p.h1s + aoffB, 16 * 2048, 16, lo2);
        } else {
          unitL(aA, aB, p.h0s + aoffA, p.h0s + aoffB, 32 * 2048, 16, lo2);
          unitL(aA, aB, p.h1s + aoffA, p.h1s + aoffB, 48 * 2048, 16, lo2);
        }
        f32x4 fA = fin3(aA), fB = fin3(aB);
        if (hh == 1) {
#pragma unroll
          for (int e = 0; e < 4; ++e) {
            ldsF[p2 * 512 + (g * 4 + e) * 16 + r] = fA[e];
            ldsF[p2 * 512 + 256 + (g * 4 + e) * 16 + r] = fB[e];
          }
        }
        __syncthreads();
        if (hh == 0) {
          const float bi = p.bhi1[n], bh = p.bhi1[512 + n];
#pragma unroll
          for (int e = 0; e < 4; ++e) {
            float hgA = ldsF[p2 * 512 + (g * 4 + e) * 16 + r];
            float hgB = ldsF[p2 * 512 + 256 + (g * 4 + e) * 16 + r];
            st2sc(p.ch1, (m0A + g * 4 + e) * H_ + n, sigf(fA[e] + bi) * tanhf(hgA + bh));
            st2sc(p.ch1, (m0B + g * 4 + e) * H_ + n, sigf(fB[e] + bi) * tanhf(hgB + bh));
          }
        }
      }
    } else if (gr == 2) {
      if (do0) {  // L0 xn/hn
        Acc3 aA = Z, aB = Z;
        if (hh == 0) {
          unitLx(aA, aB, xrA, xrB, 0, lo2);
          f32x4 fA = fin3(aA), fB = fin3(aB);
#pragma unroll
          for (int e = 0; e < 4; ++e) {
            st2sc(p.xn0, (m0A + g * 4 + e) * H_ + n, tanhf(fA[e]));
            st2sc(p.xn0, (m0B + g * 4 + e) * H_ + n, tanhf(fB[e]));
          }
        } else {
          unitL(aA, aB, p.h0s + aoffA, p.h0s + aoffB, 4 * 2048, 16, lo2);
          f32x4 fA = fin3(aA), fB = fin3(aB);
#pragma unroll
          for (int e = 0; e < 4; ++e) {
            st2sc(p.hn0, (m0A + g * 4 + e) * H_ + n, tanhf(fA[e]));
            st2sc(p.hn0, (m0B + g * 4 + e) * H_ + n, tanhf(fB[e]));
          }
        }
      }
    } else if (gr == 3) {
      if (do1) {  // L1 xn/hn
        Acc3 aA = Z, aB = Z;
        if (hh == 0) {
          unitL(aA, aB, p.h0s + aoffA, p.h0s + aoffB, 0, 16, lo2);
          f32x4 fA = fin3(aA), fB = fin3(aB);
#pragma unroll
          for (int e = 0; e < 4; ++e) {
            st2sc(p.xn1, (m0A + g * 4 + e) * H_ + n, tanhf(fA[e]));
            st2sc(p.xn1, (m0B + g * 4 + e) * H_ + n, tanhf(fB[e]));
          }
        } else {
          unitL(aA, aB, p.h1s + aoffA, p.h1s + aoffB, 16 * 2048, 16, lo2);
          f32x4 fA = fin3(aA), fB = fin3(aB);
#pragma unroll
          for (int e = 0; e < 4; ++e) {
            st2sc(p.hn1, (m0A + g * 4 + e) * H_ + n, tanhf(fA[e]));
            st2sc(p.hn1, (m0B + g * 4 + e) * H_ + n, tanhf(fB[e]));
          }
        }
      }
    }
    ++bt;
    gbar(p.ctl, bt, grp);

    // ================= phase B =================
    if (gr == 4 || gr == 5) {
      const int L = gr - 4;
      if (L ? do1 : do0) {
        const short* xn = L ? p.xn1 : p.xn0;
        const short* hn = L ? p.hn1 : p.hn0;
        const short* ch = L ? p.ch1 : p.ch0;
        Acc3 aA = Z, aB = Z;
        if (hh == 0) {
          unitL(aA, aB, xn + aoffA, xn + aoffB, 0, 16, lo2);
          unitL(aA, aB, hn + aoffA, hn + aoffB, 16 * 2048, 8, lo2);
        } else {
          unitL(aA, aB, hn + aoffA + 256, hn + aoffB + 256, 24 * 2048, 8, lo2);
          unitL(aA, aB, ch + aoffA, ch + aoffB, 32 * 2048, 16, lo2);
        }
        f32x4 fA = fin3(aA), fB = fin3(aB);
        if (hh == 1) {
#pragma unroll
          for (int e = 0; e < 4; ++e) {
            ldsF[p2 * 512 + (g * 4 + e) * 16 + r] = fA[e];
            ldsF[p2 * 512 + 256 + (g * 4 + e) * 16 + r] = fB[e];
          }
        }
        __syncthreads();
        if (hh == 0) {
          const float bc = (L ? p.bcho1 : p.bcho0)[n];
          short* o = L ? p.o1 : p.o0;
#pragma unroll
          for (int e = 0; e < 4; ++e) {
            float sA = fA[e] + ldsF[p2 * 512 + (g * 4 + e) * 16 + r];
            float sB = fB[e] + ldsF[p2 * 512 + 256 + (g * 4 + e) * 16 + r];
            st2sc(o, (m0A + g * 4 + e) * H_ + n, sigf(sA + bc));
            st2sc(o, (m0B + g * 4 + e) * H_ + n, sigf(sB + bc));
          }
        }
      }
    }
    ++bt;
    gbar(p.ctl, bt, grp);

    // ================= phase C =================
    if (gr == 6 || gr == 7) {
      const int L = gr - 6;
      if (L ? do1 : do0) {
        const short* o = L ? p.o1 : p.o0;
        Acc3 aA = Z, aB = Z;
        if (hh == 0)
          unitL(aA, aB, o + aoffA, o + aoffB, 0, 16, lo2);  // av
        else
          unitL(aA, aB, o + aoffA, o + aoffB, 16 * 2048, 16, lo2);  // bv
        f32x4 fA = fin3(aA), fB = fin3(aB);
        if (hh == 1) {
#pragma unroll
          for (int e = 0; e < 4; ++e) {
            ldsF[p2 * 512 + (g * 4 + e) * 16 + r] = fA[e];
            ldsF[p2 * 512 + 256 + (g * 4 + e) * 16 + r] = fB[e];
          }
        }
        __syncthreads();
        if (hh == 0) {
          const short* xn = L ? p.xn1 : p.xn0;
          const short* hn = L ? p.hn1 : p.hn0;
          const short* ch = L ? p.ch1 : p.ch0;
          short* hs = L ? p.h1s : p.h0s;
#pragma unroll
          for (int e = 0; e < 4; ++e) {
            {
              const int idx = (m0A + g * 4 + e) * H_ + n;
              float av = fA[e], bv = ldsF[p2 * 512 + (g * 4 + e) * 16 + r];
              float hval = av * ld2p(xn, idx) + bv * ld2p(hn, idx) +
                           (1.f - av - bv) * ld2p(ch, idx);
              st2sc(hs, idx, hval);
              if (L) stgf_sc(p.out + (size_t)(i - 1) * B_ * H_ + idx, hval);
            }
            {
              const int idx = (m0B + g * 4 + e) * H_ + n;
              float av = fB[e], bv = ldsF[p2 * 512 + 256 + (g * 4 + e) * 16 + r];
              float hval = av * ld2p(xn, idx) + bv * ld2p(hn, idx) +
                           (1.f - av - bv) * ld2p(ch, idx);
              st2sc(hs, idx, hval);
              if (L) stgf_sc(p.out + (size_t)(i - 1) * B_ * H_ + idx, hval);
            }
          }
        }
      }
    }
    ++bt;
    gbar(p.ctl, bt, grp);
  }
}

// ---------------- prologue: repack fp32 weights -> slab/role/chunk f16 2-plane ----------------
struct WP18 {
  const float* m[18];
};
__global__ void repack(WP18 wp, short* pw) {
  const long long t8 = (long long)blockIdx.x * 256 + threadIdx.x;
  const long long id = t8 * 8;
  if (id >= (long long)PK_TOT) return;
  const int s = (int)(id / SLAB_SHORTS);
  const int rem = (int)(id % SLAB_SHORTS);
  const int c = rem >> 10;
  const int r2 = rem & 1023;
  const int p = r2 >> 9;
  const int q2 = r2 & 511;
  const int rr = q2 >> 5;
  const int gg = (q2 & 31) >> 3;
  const int n0 = s * 16;
  const int pre[9] = {0, 40, 104, 124, 156, 204, 252, 284, 316};
  int gr = 0;
  while (c >= pre[gr + 1]) ++gr;
  const int cl = c - pre[gr];
  int mat, row, kc;
  switch (gr) {
    case 0:
      if (cl < 4) { mat = 0; row = n0 + rr; kc = cl; }
      else if (cl < 20) { mat = 1; row = n0 + rr; kc = cl - 4; }
      else if (cl < 24) { mat = 0; row = 512 + n0 + rr; kc = cl - 20; }
      else { mat = 1; row = 512 + n0 + rr; kc = cl - 24; }
      break;
    case 1:
      if (cl < 16) { mat = 9; row = n0 + rr; kc = cl; }
      else if (cl < 32) { mat = 10; row = n0 + rr; kc = cl - 16; }
      else if (cl < 48) { mat = 9; row = 512 + n0 + rr; kc = cl - 32; }
      else { mat = 10; row = 512 + n0 + rr; kc = cl - 48; }
      break;
    case 2:
      if (cl < 4) { mat = 2; kc = cl; } else { mat = 3; kc = cl - 4; }
      row = n0 + rr;
      break;
    case 3:
      if (cl < 16) { mat = 11; kc = cl; } else { mat = 12; kc = cl - 16; }
      row = n0 + rr;
      break;
    case 4: mat = 4 + (cl >> 4); kc = cl & 15; row = n0 + rr; break;
    case 5: mat = 13 + (cl >> 4); kc = cl & 15; row = n0 + rr; break;
    case 6: mat = 7 + (cl >> 4); kc = cl & 15; row = n0 + rr; break;
    default: mat = 16 + (cl >> 4); kc = cl & 15; row = n0 + rr; break;
  }
  const int kb = kc * 32 + gg * 8;
  const int KS = (mat == 0 || mat == 2) ? 128 : 512;
  const float* src = wp.m[mat] + (long long)row * KS + kb;
  bf16x8 o8;
#pragma unroll
  for (int e = 0; e < 8; ++e) {
    float v = src[e];
    _Float16 h0 = (_Float16)v;
    short sv;
    if (p == 0)
      sv = __builtin_bit_cast(short, h0);
    else {
      _Float16 h1 = (_Float16)((v - (float)h0) * 2048.0f);
      sv = __builtin_bit_cast(short, h1);
    }
    o8[e] = sv;
  }
  *(bf16x8*)(pw + id) = o8;
}

// ---------------- final: in-place sinrelu + LayerNorm over H on d_out ----------------
__global__ void eltm_kLN(float* __restrict__ out, const float* __restrict__ g,
                         const float* __restrict__ bta) {
  const int row = blockIdx.x * 4 + (threadIdx.x >> 6);
  const int lane = threadIdx.x & 63;
  float* r = out + (size_t)row * H_;
  float v[8];
  float s = 0.f, s2 = 0.f;
#pragma unroll
  for (int i = 0; i < 8; ++i) {
    float x = r[lane + i * 64];
    float sv = (x >= 0.f) ? (x + sinf(x)) : 0.f;
    v[i] = sv;
    s += sv;
    s2 += sv * sv;
  }
#pragma unroll
  for (int m = 1; m < 64; m <<= 1) {
    s += __shfl_xor(s, m);
    s2 += __shfl_xor(s2, m);
  }
  const float mean = s * (1.f / 512.f);
  const float var = s2 * (1.f / 512.f) - mean * mean;
  const float rstd = rsqrtf(var + 1e-5f);
#pragma unroll
  for (int i = 0; i < 8; ++i) {
    const int c = lane + i * 64;
    r[c] = (v[i] - mean) * rstd * g[c] + bta[c];
  }
}

extern "C" void kernel_launch(void* const* d_in, const int* in_sizes, int n_in,
                              void* d_out, int out_size, void* d_ws, size_t ws_size,
                              hipStream_t stream) {
#define W(i) ((const float*)d_in[i])
  short* pw = (short*)d_ws;
  short* acts = pw + (size_t)PK_TOT;
  short* h0s = acts;
  short* h1s = acts + ASZ;
  short* xn0 = acts + 2 * ASZ;
  short* hn0 = acts + 3 * ASZ;
  short* ch0 = acts + 4 * ASZ;
  short* xn1 = acts + 5 * ASZ;
  short* hn1 = acts + 6 * ASZ;
  short* ch1 = acts + 7 * ASZ;
  short* o0 = acts + 8 * ASZ;
  short* o1 = acts + 9 * ASZ;
  unsigned int* ctl = (unsigned int*)(acts + 10 * (size_t)ASZ);
  float* out = (float*)d_out;

  WP18 wps;
  const int srcIdx[18] = {1,  2,  4,  5,  6,  7,  8,  10, 11,
                          12, 13, 15, 16, 17, 18, 19, 21, 22};
  for (int i = 0; i < 18; ++i) wps.m[i] = W(srcIdx[i]);

  repack<<<PK_TOT / 8 / 256, 256, 0, stream>>>(wps, pw);
  hipMemsetAsync(h0s, 0, (size_t)2 * ASZ * sizeof(short), stream);
  hipMemsetAsync(ctl, 0, 2048, stream);

  hipFuncSetAttribute((const void*)eltm_p, hipFuncAttributeMaxDynamicSharedMemorySize,
                      139264);
  PP pa;
  pa.x = (const float*)d_in[0];
  pa.pw = pw;
  pa.h0s = h0s;
  pa.h1s = h1s;
  pa.xn0 = xn0;
  pa.hn0 = hn0;
  pa.ch0 = ch0;
  pa.xn1 = xn1;
  pa.hn1 = hn1;
  pa.ch1 = ch1;
  pa.o0 = o0;
  pa.o1 = o1;
  pa.bhi0 = W(3);
  pa.bcho0 = W(9);
  pa.bhi1 = W(14);
  pa.bcho1 = W(20);
  pa.out = out;
  pa.ctl = ctl;
  eltm_p<<<NB_, 512, 139264, stream>>>(pa);

  eltm_kLN<<<16384, 256, 0, stream>>>(out, W(23), W(24));
#undef W
}

// Round 11
// 51624.561 us; speedup vs baseline: 1.8417x; 1.8417x over previous
//
#include <hip/hip_runtime.h>
#include <hip/hip_bf16.h>

#define S_ 512
#define B_ 128
#define D_ 128
#define H_ 512
#define NB_ 256

// ---- packed f16 2-plane weight layout: 32 slabs x 316 chunks x 1024 shorts ----
// chunk = 1024 shorts = 2 planes x 512; in-chunk [row r(0..15)][k: gg*8+e] per plane.
// A section chunks 0..155 (r7 segment order), B 156..251 (io|ho|cho per layer),
// C 252..315 (u-blocks: u<2 -> j=s>>1, u>=2 -> j=16+(s>>1); mat a/b by u&1; L=s&1).
#define SLAB_SHORTS 323584
#define PK_TOT 10354688
#define APLANE 65536
#define ASZ    131072  // 2*APLANE

#define SC1F 4.8828125e-4f          // 2^-11
#define SC2F 2.384185791015625e-7f  // 2^-22

typedef short bf16x8 __attribute__((ext_vector_type(8)));
typedef _Float16 f16x8 __attribute__((ext_vector_type(8)));
typedef int i32x4 __attribute__((ext_vector_type(4)));
typedef float f32x4 __attribute__((ext_vector_type(4)));

__device__ __forceinline__ float sigf(float x) { return 1.0f / (1.0f + expf(-x)); }

// plain cached 16B load
__device__ __forceinline__ i32x4 ldg(const short* p) {
  i32x4 o;
  asm volatile("global_load_dwordx4 %0, %1, off" : "=v"(o) : "v"(p));
  return o;
}
#define VMDRAIN()                                    \
  do {                                               \
    asm volatile("s_waitcnt vmcnt(0)" ::: "memory"); \
    __builtin_amdgcn_sched_barrier(0);               \
  } while (0)

// sc1 write-through store (agent-visible after vmcnt(0); no dirty L2 line)
__device__ __forceinline__ void stg16s(short* p, unsigned int v) {
  asm volatile("global_store_short %0, %1, off sc1" ::"v"(p), "v"(v) : "memory");
}
// f16 2-plane split-store (sc1, cross-XCD) / plain cached gather (post-inv)
__device__ __forceinline__ void st2sc(short* buf, int idx, float v) {
  _Float16 h0 = (_Float16)v;
  _Float16 h1 = (_Float16)((v - (float)h0) * 2048.0f);
  stg16s(buf + idx, (unsigned int)__builtin_bit_cast(unsigned short, h0));
  stg16s(buf + idx + APLANE, (unsigned int)__builtin_bit_cast(unsigned short, h1));
}
__device__ __forceinline__ float ld2p(const short* buf, int idx) {
  float a = (float)__builtin_bit_cast(_Float16, buf[idx]);
  float b = (float)__builtin_bit_cast(_Float16, buf[idx + APLANE]);
  return a + b * SC1F;
}

#define MFMAH(a, b, c) __builtin_amdgcn_mfma_f32_16x16x32_f16(a, b, c, 0, 0, 0)
#define BC16(x) __builtin_bit_cast(f16x8, x)

__device__ __forceinline__ void mac4(f32x4& c0, f32x4& c1, f32x4& c2, const f16x8& a0,
                                     const f16x8& a1, const f16x8& w0, const f16x8& w1) {
  c0 = MFMAH(a0, w0, c0);
  c1 = MFMAH(a0, w1, c1);
  c1 = MFMAH(a1, w0, c1);
  c2 = MFMAH(a1, w1, c2);
}
__device__ __forceinline__ f32x4 fin3(const f32x4& c0, const f32x4& c1,
                                      const f32x4& c2) {
  f32x4 o;
#pragma unroll
  for (int e = 0; e < 4; ++e) o[e] = c0[e] + SC1F * c1[e] + SC2F * c2[e];
  return o;
}

// GEMV unit: A 2-plane f16 activations (plain cached), W packed stream (plain cached;
// same-XCD blocks of the same slab share L2 fills). lane offset lo = r*32+g*8 shorts.
__device__ __forceinline__ void unitP(f32x4& c0, f32x4& c1, f32x4& c2,
                                      const short* aBase, const short* slab, int nks,
                                      int lo) {
  for (int q = 0; q < nks; q += 4) {
    i32x4 A0[4], A1[4], W0[4], W1[4];
#pragma unroll
    for (int u = 0; u < 4; ++u) {
      const short* wp = slab + (size_t)(q + u) * 1024 + lo;
      W0[u] = ldg(wp);
      W1[u] = ldg(wp + 512);
      const short* ap = aBase + (q + u) * 32;
      A0[u] = ldg(ap);
      A1[u] = ldg(ap + APLANE);
    }
    VMDRAIN();
#pragma unroll
    for (int u = 0; u < 4; ++u)
      mac4(c0, c1, c2, BC16(A0[u]), BC16(A1[u]), BC16(W0[u]), BC16(W1[u]));
  }
}

// x-part (4 kchunks of fp32 x, split on the fly)
__device__ __forceinline__ void unitPx(f32x4& c0, f32x4& c1, f32x4& c2,
                                       const float* xRow, const short* slab, int lo) {
  i32x4 W0[4], W1[4];
  f16x8 A0[4], A1[4];
#pragma unroll
  for (int u = 0; u < 4; ++u) {
    const short* wp = slab + (size_t)u * 1024 + lo;
    W0[u] = ldg(wp);
    W1[u] = ldg(wp + 512);
#pragma unroll
    for (int e = 0; e < 8; ++e) {
      float v = xRow[u * 32 + e];
      _Float16 h0 = (_Float16)v;
      A0[u][e] = h0;
      A1[u][e] = (_Float16)((v - (float)h0) * 2048.0f);
    }
  }
  VMDRAIN();
#pragma unroll
  for (int u = 0; u < 4; ++u) mac4(c0, c1, c2, A0[u], A1[u], BC16(W0[u]), BC16(W1[u]));
}

// ---- atomics (agent scope, relaxed, monotonic) ----
__device__ __forceinline__ unsigned int afa(unsigned int* p) {
  return __hip_atomic_fetch_add(p, 1u, __ATOMIC_RELAXED, __HIP_MEMORY_SCOPE_AGENT);
}
__device__ __forceinline__ unsigned int ald(const unsigned int* p) {
  return __hip_atomic_load(p, __ATOMIC_RELAXED, __HIP_MEMORY_SCOPE_AGENT);
}

// global grouped barrier (r8-validated): 8 groups x 32, monotonic; then sc1 inv.
// ctl[grp*32] group counters, ctl[256] master, ctl[288] gen.
__device__ __forceinline__ void gbar(unsigned int* ctl, unsigned int t, int grp) {
  asm volatile("s_waitcnt vmcnt(0) lgkmcnt(0)" ::: "memory");  // release sc1 stores
  __syncthreads();
  if (threadIdx.x == 0) {
    unsigned int a = afa(&ctl[grp * 32]);
    if (a == t * 32u - 1u) {
      unsigned int m = afa(&ctl[256]);
      if (m == t * 8u - 1u)
        __hip_atomic_store(&ctl[288], t, __ATOMIC_RELAXED, __HIP_MEMORY_SCOPE_AGENT);
    }
    int guard = 0;
    while (ald(&ctl[288]) < t) {
      __builtin_amdgcn_s_sleep(2);
      if (++guard > (1 << 24)) break;  // bail: wrong answer beats hang
    }
  }
  __syncthreads();
  asm volatile("buffer_inv sc1" ::: "memory");  // acquire: drop stale clean copies
  __builtin_amdgcn_sched_barrier(0);
}

struct PP {
  const float* x;
  const short* pw;
  short* h0s;
  short* h1s;
  short* xn0;
  short* hn0;
  short* ch0;
  short* xn1;
  short* hn1;
  short* ch1;
  short* o0;
  short* o1;
  const float* bhi0;
  const float* bcho0;
  const float* bhi1;
  const float* bcho1;
  float* out;
  unsigned int* ctl;
};

// Deterministic bijective 2-D partition (no self-org):
//   s = (bid&7)*4 + (bid>>6)    (slab 0..31)
//   row0 = ((bid>>3)&7)*16      (row-tile 0..7)
// Under round-robin blockIdx->XCD placement, a slab's 8 row-tile blocks share one
// XCD (L2 weight sharing); if placement differs only perf changes, never mapping.
__global__ __launch_bounds__(512, 1) void eltm_p(PP p) {
  extern __shared__ char smem[];
  float* ldsF = (float*)smem;  // 8KB combine scratch
  const int tid = threadIdx.x;
  const int lane = tid & 63;
  const int w = tid >> 6;
  const int r = lane & 15;
  const int g = lane >> 4;
  const int lo = r * 32 + g * 8;
  const f32x4 z = {0.f, 0.f, 0.f, 0.f};

  const int bid = blockIdx.x;
  const int s = (bid & 7) * 4 + (bid >> 6);
  const int row0 = ((bid >> 3) & 7) * 16;
  const int grp = bid & 7;

  const int aoff = (row0 + r) * H_ + g * 8;
  const int n = s * 16 + r;
  // A-section wave bases (shorts): r7 segment order
  static const int preW[8] = {0, 20480, 40960, 45056, 61440, 94208, 126976, 143360};

  unsigned int bt = 0;
  for (int i = 0; i <= S_; ++i) {
    const int do0 = i < S_;
    const int do1 = i >= 1;
    const float* xr = p.x + ((size_t)i * B_ + row0 + r) * D_ + g * 8;
    const short* slabA = p.pw + (size_t)s * SLAB_SHORTS;

    // ================= phase A =================
    {
      f32x4 c0 = z, c1 = z, c2 = z;
      f32x4 fin = z;
      switch (w) {
        case 0:
        case 1:
          if (do0) {
            const short* sl = slabA + preW[w];
            unitPx(c0, c1, c2, xr, sl, lo);
            unitP(c0, c1, c2, p.h0s + aoff, sl + 4096, 16, lo);
            fin = fin3(c0, c1, c2);
          }
          break;
        case 2:
          if (do0) {
            unitPx(c0, c1, c2, xr, slabA + preW[2], lo);
            fin = fin3(c0, c1, c2);
#pragma unroll
            for (int e = 0; e < 4; ++e)
              st2sc(p.xn0, (row0 + g * 4 + e) * H_ + n, tanhf(fin[e]));
          }
          break;
        case 3:
          if (do0) {
            unitP(c0, c1, c2, p.h0s + aoff, slabA + preW[3], 16, lo);
            fin = fin3(c0, c1, c2);
#pragma unroll
            for (int e = 0; e < 4; ++e)
              st2sc(p.hn0, (row0 + g * 4 + e) * H_ + n, tanhf(fin[e]));
          }
          break;
        case 4:
        case 5:
          if (do1) {
            const short* sl = slabA + preW[w];
            unitP(c0, c1, c2, p.h0s + aoff, sl, 16, lo);
            unitP(c0, c1, c2, p.h1s + aoff, sl + 16384, 16, lo);
            fin = fin3(c0, c1, c2);
          }
          break;
        case 6:
          if (do1) {
            unitP(c0, c1, c2, p.h0s + aoff, slabA + preW[6], 16, lo);
            fin = fin3(c0, c1, c2);
#pragma unroll
            for (int e = 0; e < 4; ++e)
              st2sc(p.xn1, (row0 + g * 4 + e) * H_ + n, tanhf(fin[e]));
          }
          break;
        default:
          if (do1) {
            unitP(c0, c1, c2, p.h1s + aoff, slabA + preW[7], 16, lo);
            fin = fin3(c0, c1, c2);
#pragma unroll
            for (int e = 0; e < 4; ++e)
              st2sc(p.hn1, (row0 + g * 4 + e) * H_ + n, tanhf(fin[e]));
          }
          break;
      }
      if ((w == 1 && do0) || (w == 5 && do1)) {
#pragma unroll
        for (int e = 0; e < 4; ++e)
          ldsF[(w == 5 ? 256 : 0) + (g * 4 + e) * 16 + r] = fin[e];
      }
      __syncthreads();
      if (w == 0 && do0) {
        const float bi = p.bhi0[n], bh = p.bhi0[512 + n];
#pragma unroll
        for (int e = 0; e < 4; ++e) {
          float hgv = ldsF[(g * 4 + e) * 16 + r];
          st2sc(p.ch0, (row0 + g * 4 + e) * H_ + n, sigf(fin[e] + bi) * tanhf(hgv + bh));
        }
      }
      if (w == 4 && do1) {
        const float bi = p.bhi1[n], bh = p.bhi1[512 + n];
#pragma unroll
        for (int e = 0; e < 4; ++e) {
          float hgv = ldsF[256 + (g * 4 + e) * 16 + r];
          st2sc(p.ch1, (row0 + g * 4 + e) * H_ + n, sigf(fin[e] + bi) * tanhf(hgv + bh));
        }
      }
      __syncthreads();
    }
    ++bt;
    gbar(p.ctl, bt, grp);

    // ================= phase B =================
    {
      const int L = w >> 2;
      const int tt = w & 3;
      const int ok = L ? do1 : do0;
      f32x4 fA = z;
      if (ok) {
        f32x4 c0 = z, c1 = z, c2 = z;
        const short* slab =
            p.pw + (size_t)s * SLAB_SHORTS + 156 * 1024 + (size_t)L * 49152;
        const short* xn = L ? p.xn1 : p.xn0;
        const short* hn = L ? p.hn1 : p.hn0;
        const short* ch = L ? p.ch1 : p.ch0;
        if (tt == 0)
          unitP(c0, c1, c2, xn + aoff, slab, 16, lo);
        else if (tt == 1)
          unitP(c0, c1, c2, hn + aoff, slab + 16384, 16, lo);
        else if (tt == 2)
          unitP(c0, c1, c2, ch + aoff, slab + 32768, 8, lo);
        else
          unitP(c0, c1, c2, ch + aoff + 256, slab + 40960, 8, lo);
        fA = fin3(c0, c1, c2);
#pragma unroll
        for (int e = 0; e < 4; ++e) ldsF[w * 256 + (g * 4 + e) * 16 + r] = fA[e];
      }
      __syncthreads();
      if ((w == 0 && do0) || (w == 4 && do1)) {
        const float bc = (w == 4 ? p.bcho1 : p.bcho0)[n];
        short* o = w == 4 ? p.o1 : p.o0;
#pragma unroll
        for (int e = 0; e < 4; ++e) {
          const int q = (g * 4 + e) * 16 + r;
          float sum = ldsF[w * 256 + q] + ldsF[(w + 1) * 256 + q] +
                      ldsF[(w + 2) * 256 + q] + ldsF[(w + 3) * 256 + q];
          st2sc(o, (row0 + g * 4 + e) * H_ + n, sigf(sum + bc));
        }
      }
      __syncthreads();
    }
    ++bt;
    gbar(p.ctl, bt, grp);

    // ================= phase C =================
    {
      const int L = s & 1;
      const int ok = L ? do1 : do0;
      const int u = w >> 1;
      const int h = w & 1;
      if (ok) {
        f32x4 c0 = z, c1 = z, c2 = z;
        const short* slab = p.pw + (size_t)s * SLAB_SHORTS + 252 * 1024 +
                            (size_t)u * 16384 + (size_t)h * 8192;
        const short* o = L ? p.o1 : p.o0;
        unitP(c0, c1, c2, o + aoff + h * 256, slab, 8, lo);
        f32x4 fin = fin3(c0, c1, c2);
#pragma unroll
        for (int e = 0; e < 4; ++e) ldsF[w * 256 + (g * 4 + e) * 16 + r] = fin[e];
      }
      __syncthreads();
      if ((w == 0 || w == 4) && ok) {
        const int j = (w == 0) ? (s >> 1) : (16 + (s >> 1));
        const int ub = (w == 0) ? 0 : 4;
        const short* xn = L ? p.xn1 : p.xn0;
        const short* hn = L ? p.hn1 : p.hn0;
        const short* ch = L ? p.ch1 : p.ch0;
        short* hs = L ? p.h1s : p.h0s;
#pragma unroll
        for (int e = 0; e < 4; ++e) {
          const int q = (g * 4 + e) * 16 + r;
          const float av = ldsF[(ub + 0) * 256 + q] + ldsF[(ub + 1) * 256 + q];
          const float bv = ldsF[(ub + 2) * 256 + q] + ldsF[(ub + 3) * 256 + q];
          const int idx = (row0 + g * 4 + e) * H_ + j * 16 + r;
          const float hval = av * ld2p(xn, idx) + bv * ld2p(hn, idx) +
                             (1.f - av - bv) * ld2p(ch, idx);
          st2sc(hs, idx, hval);
          if (L) p.out[(size_t)(i - 1) * B_ * H_ + idx] = hval;
        }
      }
      __syncthreads();
    }
    ++bt;
    gbar(p.ctl, bt, grp);
  }
}

// ---------------- prologue: repack fp32 weights -> slab/chunk f16 2-plane ----------------
// A-section uses r7's VALIDATED segment order matching the kernel's preW:
//   seg chunks {0,20,40,44,60,92,124,140,156}:
//   [L0ig: xi(4)+hi(16)] [L0hg: xi(4)+hi(16)] [ox0(4)] [oh0(16)]
//   [L1ig: xi(16)+hi(16)] [L1hg: xi(16)+hi(16)] [ox1(16)] [oh1(16)]
struct WP18 {
  const float* m[18];
};
__global__ void repack(WP18 wp, short* pw) {
  const long long t8 = (long long)blockIdx.x * 256 + threadIdx.x;
  const long long id = t8 * 8;
  if (id >= (long long)PK_TOT) return;
  const int s = (int)(id / SLAB_SHORTS);
  const int rem = (int)(id % SLAB_SHORTS);
  const int c = rem >> 10;        // chunk 0..315
  const int r2 = rem & 1023;
  const int p = r2 >> 9;          // plane
  const int q2 = r2 & 511;
  const int rr = q2 >> 5;         // row-in-tile 0..15
  const int gg = (q2 & 31) >> 3;  // k-subgroup 0..3
  const int n0 = s * 16;
  int mat, row, kb;
  if (c < 156) {
    // ---- A section, r7 segment order ----
    const int segA[9] = {0, 20, 40, 44, 60, 92, 124, 140, 156};
    int sg = 0;
    while (c >= segA[sg + 1]) ++sg;
    const int cl = c - segA[sg];
    const int kin = cl * 32 + gg * 8;
    switch (sg) {
      case 0:
        row = n0 + rr;
        if (kin < 128) { mat = 0; kb = kin; } else { mat = 1; kb = kin - 128; }
        break;
      case 1:
        row = 512 + n0 + rr;
        if (kin < 128) { mat = 0; kb = kin; } else { mat = 1; kb = kin - 128; }
        break;
      case 2: mat = 2; row = n0 + rr; kb = kin; break;
      case 3: mat = 3; row = n0 + rr; kb = kin; break;
      case 4:
        row = n0 + rr;
        if (kin < 512) { mat = 9; kb = kin; } else { mat = 10; kb = kin - 512; }
        break;
      case 5:
        row = 512 + n0 + rr;
        if (kin < 512) { mat = 9; kb = kin; } else { mat = 10; kb = kin - 512; }
        break;
      case 6: mat = 11; row = n0 + rr; kb = kin; break;
      default: mat = 12; row = n0 + rr; kb = kin; break;
    }
  } else if (c < 252) {
    // ---- B section: [io(16)|ho(16)|cho(16)] x {L0, L1} ----
    const int cl = c - 156;
    const int L = cl >= 48;
    const int cc = cl - (L ? 48 : 0);
    mat = (L ? 13 : 4) + (cc >> 4);
    row = n0 + rr;
    kb = (cc & 15) * 32 + gg * 8;
  } else {
    // ---- C section: u-blocks of 16 chunks; u<2 -> j=s>>1, u>=2 -> j=16+(s>>1) ----
    const int cc = c - 252;  // 0..63
    const int u = cc >> 4;
    const int L = s & 1;
    const int j = (u < 2) ? (s >> 1) : (16 + (s >> 1));
    mat = (L ? 16 : 7) + (u & 1);
    row = j * 16 + rr;
    kb = (cc & 15) * 32 + gg * 8;
  }
  const int KS = (mat == 0 || mat == 2) ? 128 : 512;
  const float* src = wp.m[mat] + (long long)row * KS + kb;
  bf16x8 o8;
#pragma unroll
  for (int e = 0; e < 8; ++e) {
    float v = src[e];
    _Float16 h0 = (_Float16)v;
    short sv;
    if (p == 0)
      sv = __builtin_bit_cast(short, h0);
    else {
      _Float16 h1 = (_Float16)((v - (float)h0) * 2048.0f);
      sv = __builtin_bit_cast(short, h1);
    }
    o8[e] = sv;
  }
  *(bf16x8*)(pw + id) = o8;
}

// ---------------- final: in-place sinrelu + LayerNorm over H on d_out ----------------
__global__ void eltm_kLN(float* __restrict__ out, const float* __restrict__ g,
                         const float* __restrict__ bta) {
  const int row = blockIdx.x * 4 + (threadIdx.x >> 6);
  const int lane = threadIdx.x & 63;
  float* r = out + (size_t)row * H_;
  float v[8];
  float s = 0.f, s2 = 0.f;
#pragma unroll
  for (int i = 0; i < 8; ++i) {
    float x = r[lane + i * 64];
    float sv = (x >= 0.f) ? (x + sinf(x)) : 0.f;
    v[i] = sv;
    s += sv;
    s2 += sv * sv;
  }
#pragma unroll
  for (int m = 1; m < 64; m <<= 1) {
    s += __shfl_xor(s, m);
    s2 += __shfl_xor(s2, m);
  }
  const float mean = s * (1.f / 512.f);
  const float var = s2 * (1.f / 512.f) - mean * mean;
  const float rstd = rsqrtf(var + 1e-5f);
#pragma unroll
  for (int i = 0; i < 8; ++i) {
    const int c = lane + i * 64;
    r[c] = (v[i] - mean) * rstd * g[c] + bta[c];
  }
}

extern "C" void kernel_launch(void* const* d_in, const int* in_sizes, int n_in,
                              void* d_out, int out_size, void* d_ws, size_t ws_size,
                              hipStream_t stream) {
#define W(i) ((const float*)d_in[i])
  short* pw = (short*)d_ws;
  short* acts = pw + (size_t)PK_TOT;
  short* h0s = acts;
  short* h1s = acts + ASZ;
  short* xn0 = acts + 2 * ASZ;
  short* hn0 = acts + 3 * ASZ;
  short* ch0 = acts + 4 * ASZ;
  short* xn1 = acts + 5 * ASZ;
  short* hn1 = acts + 6 * ASZ;
  short* ch1 = acts + 7 * ASZ;
  short* o0 = acts + 8 * ASZ;
  short* o1 = acts + 9 * ASZ;
  unsigned int* ctl = (unsigned int*)(acts + 10 * (size_t)ASZ);
  float* out = (float*)d_out;

  WP18 wps;
  const int srcIdx[18] = {1,  2,  4,  5,  6,  7,  8,  10, 11,
                          12, 13, 15, 16, 17, 18, 19, 21, 22};
  for (int i = 0; i < 18; ++i) wps.m[i] = W(srcIdx[i]);

  repack<<<PK_TOT / 8 / 256, 256, 0, stream>>>(wps, pw);
  hipMemsetAsync(h0s, 0, (size_t)2 * ASZ * sizeof(short), stream);
  hipMemsetAsync(ctl, 0, 4096, stream);

  hipFuncSetAttribute((const void*)eltm_p, hipFuncAttributeMaxDynamicSharedMemorySize,
                      98304);
  PP pa;
  pa.x = (const float*)d_in[0];
  pa.pw = pw;
  pa.h0s = h0s;
  pa.h1s = h1s;
  pa.xn0 = xn0;
  pa.hn0 = hn0;
  pa.ch0 = ch0;
  pa.xn1 = xn1;
  pa.hn1 = hn1;
  pa.ch1 = ch1;
  pa.o0 = o0;
  pa.o1 = o1;
  pa.bhi0 = W(3);
  pa.bcho0 = W(9);
  pa.bhi1 = W(14);
  pa.bcho1 = W(20);
  pa.out = out;
  pa.ctl = ctl;
  eltm_p<<<NB_, 512, 98304, stream>>>(pa);

  eltm_kLN<<<16384, 256, 0, stream>>>(out, W(23), W(24));
#undef W
}

// Round 12
// 32544.058 us; speedup vs baseline: 2.9215x; 1.5863x over previous
//
#include <hip/hip_runtime.h>
#include <hip/hip_bf16.h>

#define S_ 512
#define B_ 128
#define D_ 128
#define H_ 512
#define NB_ 256

// ---- packed f16 2-plane weight layout: 32 slabs x 316 chunks x 1024 shorts ----
#define SLAB_SHORTS 323584
#define PK_TOT 10354688
#define APLANE 65536
#define ASZ    131072  // 2*APLANE

#define SC1F 4.8828125e-4f          // 2^-11
#define SC2F 2.384185791015625e-7f  // 2^-22

// LDS map (bytes): ldsF scratch 0..8191; stage A0 @8192 (32KB); stage A1 @40960 (32KB)
#define LDSF 0
#define LDSA0 8192
#define LDSA1 40960
#define LDSTOT 73728

typedef short bf16x8 __attribute__((ext_vector_type(8)));
typedef _Float16 f16x8 __attribute__((ext_vector_type(8)));
typedef int i32x4 __attribute__((ext_vector_type(4)));
typedef float f32x4 __attribute__((ext_vector_type(4)));

__device__ __forceinline__ float sigf(float x) { return 1.0f / (1.0f + expf(-x)); }

// plain cached 16B load (weights/x only — L2-resident, never invalidated)
__device__ __forceinline__ i32x4 ldg(const short* p) {
  i32x4 o;
  asm volatile("global_load_dwordx4 %0, %1, off" : "=v"(o) : "v"(p));
  return o;
}
// sc1 coherent 16B load (activations — reads MALL truth)
__device__ __forceinline__ i32x4 ldgs(const short* p) {
  i32x4 o;
  asm volatile("global_load_dwordx4 %0, %1, off sc1" : "=v"(o) : "v"(p));
  return o;
}
__device__ __forceinline__ unsigned int ldus(const short* p) {
  unsigned int o;
  asm volatile("global_load_ushort %0, %1, off sc1" : "=v"(o) : "v"(p));
  return o;
}
#define VMDRAIN()                                    \
  do {                                               \
    asm volatile("s_waitcnt vmcnt(0)" ::: "memory"); \
    __builtin_amdgcn_sched_barrier(0);               \
  } while (0)

// sc1 write-through store (agent-visible after vmcnt(0); no dirty L2 line)
__device__ __forceinline__ void stg16s(short* p, unsigned int v) {
  asm volatile("global_store_short %0, %1, off sc1" ::"v"(p), "v"(v) : "memory");
}
__device__ __forceinline__ void st2sc(short* buf, int idx, float v) {
  _Float16 h0 = (_Float16)v;
  _Float16 h1 = (_Float16)((v - (float)h0) * 2048.0f);
  stg16s(buf + idx, (unsigned int)__builtin_bit_cast(unsigned short, h0));
  stg16s(buf + idx + APLANE, (unsigned int)__builtin_bit_cast(unsigned short, h1));
}
__device__ __forceinline__ float h2f(unsigned int u) {
  return (float)__builtin_bit_cast(_Float16, (unsigned short)(u & 0xffffu));
}

#define MFMAH(a, b, c) __builtin_amdgcn_mfma_f32_16x16x32_f16(a, b, c, 0, 0, 0)
#define BC16(x) __builtin_bit_cast(f16x8, x)

__device__ __forceinline__ void mac4(f32x4& c0, f32x4& c1, f32x4& c2, const f16x8& a0,
                                     const f16x8& a1, const f16x8& w0, const f16x8& w1) {
  c0 = MFMAH(a0, w0, c0);
  c1 = MFMAH(a0, w1, c1);
  c1 = MFMAH(a1, w0, c1);
  c2 = MFMAH(a1, w1, c2);
}
__device__ __forceinline__ f32x4 fin3(const f32x4& c0, const f32x4& c1,
                                      const f32x4& c2) {
  f32x4 o;
#pragma unroll
  for (int e = 0; e < 4; ++e) o[e] = c0[e] + SC1F * c1[e] + SC2F * c2[e];
  return o;
}

// cooperative stage: 16-row x 512-k 2-plane activation slice -> LDS (swizzled).
// 4096 x 16B units over 512 threads, 4-deep MLP. Call with ALL threads, uniform cond.
__device__ __forceinline__ void stageAct(const short* src, int ldsBase) {
  extern __shared__ char smem[];
  i32x4 v[4];
  int ad[4];
#pragma unroll
  for (int t = 0; t < 4; ++t) {
    const int c = (int)threadIdx.x + t * 512;
    const int pl = c >> 10;
    const int u = c & 1023;
    const int rr = u >> 6;
    const int k16 = u & 63;
    v[t] = ldgs(src + pl * APLANE + rr * H_ + k16 * 8);
    ad[t] = ldsBase + pl * 16384 + ((rr * 1024 + k16 * 16) ^ ((rr & 7) << 4));
  }
  VMDRAIN();
#pragma unroll
  for (int t = 0; t < 4; ++t) *(i32x4*)(smem + ad[t]) = v[t];
}

// GEMV unit: A from LDS (staged, swizzled), W plain global (L2-hot).
__device__ __forceinline__ void unitL(f32x4& c0, f32x4& c1, f32x4& c2, int ldsBase,
                                      int qoff, const short* slabW, int nks, int lo,
                                      int r, int g) {
  extern __shared__ char smem[];
  for (int q = 0; q < nks; q += 4) {
    i32x4 W0[4], W1[4];
#pragma unroll
    for (int u = 0; u < 4; ++u) {
      const short* wp = slabW + (size_t)(q + u) * 1024 + lo;
      W0[u] = ldg(wp);
      W1[u] = ldg(wp + 512);
    }
    bf16x8 A0[4], A1[4];
#pragma unroll
    for (int u = 0; u < 4; ++u) {
      const int ka = ((r * 1024 + (q + qoff + u) * 64 + g * 16) ^ ((r & 7) << 4));
      A0[u] = *(const bf16x8*)(smem + ldsBase + ka);
      A1[u] = *(const bf16x8*)(smem + ldsBase + 16384 + ka);
    }
    VMDRAIN();
#pragma unroll
    for (int u = 0; u < 4; ++u)
      mac4(c0, c1, c2, BC16(A0[u]), BC16(A1[u]), BC16(W0[u]), BC16(W1[u]));
  }
}

// GEMV unit: A direct sc1 (no redundancy case), deep 8-chunk batches; W plain.
__device__ __forceinline__ void unitS(f32x4& c0, f32x4& c1, f32x4& c2,
                                      const short* aBase, const short* slabW, int nks,
                                      int lo) {
  for (int q = 0; q < nks; q += 8) {
    i32x4 A0[8], A1[8], W0[8], W1[8];
#pragma unroll
    for (int u = 0; u < 8; ++u) {
      A0[u] = ldgs(aBase + (q + u) * 32);
      A1[u] = ldgs(aBase + (q + u) * 32 + APLANE);
      const short* wp = slabW + (size_t)(q + u) * 1024 + lo;
      W0[u] = ldg(wp);
      W1[u] = ldg(wp + 512);
    }
    VMDRAIN();
#pragma unroll
    for (int u = 0; u < 8; ++u)
      mac4(c0, c1, c2, BC16(A0[u]), BC16(A1[u]), BC16(W0[u]), BC16(W1[u]));
  }
}

// x-part (4 kchunks of fp32 x, plain cached, split on the fly)
__device__ __forceinline__ void unitPx(f32x4& c0, f32x4& c1, f32x4& c2,
                                       const float* xRow, const short* slab, int lo) {
  i32x4 W0[4], W1[4];
  f16x8 A0[4], A1[4];
#pragma unroll
  for (int u = 0; u < 4; ++u) {
    const short* wp = slab + (size_t)u * 1024 + lo;
    W0[u] = ldg(wp);
    W1[u] = ldg(wp + 512);
#pragma unroll
    for (int e = 0; e < 8; ++e) {
      float v = xRow[u * 32 + e];
      _Float16 h0 = (_Float16)v;
      A0[u][e] = h0;
      A1[u][e] = (_Float16)((v - (float)h0) * 2048.0f);
    }
  }
  VMDRAIN();
#pragma unroll
  for (int u = 0; u < 4; ++u) mac4(c0, c1, c2, A0[u], A1[u], BC16(W0[u]), BC16(W1[u]));
}

// ---- atomics (agent scope, relaxed, monotonic) ----
__device__ __forceinline__ unsigned int afa(unsigned int* p) {
  return __hip_atomic_fetch_add(p, 1u, __ATOMIC_RELAXED, __HIP_MEMORY_SCOPE_AGENT);
}
__device__ __forceinline__ unsigned int ald(const unsigned int* p) {
  return __hip_atomic_load(p, __ATOMIC_RELAXED, __HIP_MEMORY_SCOPE_AGENT);
}

// global grouped barrier; L1-only invalidate (weights in L2 stay resident).
__device__ __forceinline__ void gbar(unsigned int* ctl, unsigned int t, int grp) {
  asm volatile("s_waitcnt vmcnt(0) lgkmcnt(0)" ::: "memory");  // release sc1 stores
  __syncthreads();
  if (threadIdx.x == 0) {
    unsigned int a = afa(&ctl[grp * 32]);
    if (a == t * 32u - 1u) {
      unsigned int m = afa(&ctl[256]);
      if (m == t * 8u - 1u)
        __hip_atomic_store(&ctl[288], t, __ATOMIC_RELAXED, __HIP_MEMORY_SCOPE_AGENT);
    }
    int guard = 0;
    while (ald(&ctl[288]) < t) {
      __builtin_amdgcn_s_sleep(2);
      if (++guard > (1 << 24)) break;  // bail: wrong answer beats hang
    }
  }
  __syncthreads();
  asm volatile("buffer_inv sc0" ::: "memory");  // L1 only
  __builtin_amdgcn_sched_barrier(0);
}

struct PP {
  const float* x;
  const short* pw;
  short* h0s;
  short* h1s;
  short* xn0;
  short* hn0;
  short* ch0;
  short* xn1;
  short* hn1;
  short* ch1;
  short* o0;
  short* o1;
  const float* bhi0;
  const float* bcho0;
  const float* bhi1;
  const float* bcho1;
  float* out;
  unsigned int* ctl;
};

// Deterministic bijective 2-D partition: s = (bid&7)*4 + (bid>>6), row0 = ((bid>>3)&7)*16
__global__ __launch_bounds__(512, 1) void eltm_p(PP p) {
  extern __shared__ char smem[];
  float* ldsF = (float*)smem;
  const int tid = threadIdx.x;
  const int lane = tid & 63;
  const int w = tid >> 6;
  const int r = lane & 15;
  const int g = lane >> 4;
  const int lo = r * 32 + g * 8;
  const f32x4 z = {0.f, 0.f, 0.f, 0.f};

  const int bid = blockIdx.x;
  const int s = (bid & 7) * 4 + (bid >> 6);
  const int row0 = ((bid >> 3) & 7) * 16;
  const int grp = bid & 7;

  const int aoff = (row0 + r) * H_ + g * 8;
  const int n = s * 16 + r;
  static const int preW[8] = {0, 20480, 40960, 45056, 61440, 94208, 126976, 143360};

  unsigned int bt = 0;
  for (int i = 0; i <= S_; ++i) {
    const int do0 = i < S_;
    const int do1 = i >= 1;
    const float* xr = p.x + ((size_t)i * B_ + row0 + r) * D_ + g * 8;
    const short* slabA = p.pw + (size_t)s * SLAB_SHORTS;

    // ================= phase A =================
    {
      stageAct(p.h0s + row0 * H_, LDSA0);
      if (do1) stageAct(p.h1s + row0 * H_, LDSA1);
      __syncthreads();
      f32x4 c0 = z, c1 = z, c2 = z;
      f32x4 fin = z;
      switch (w) {
        case 0:
        case 1:
          if (do0) {
            const short* sl = slabA + preW[w];
            unitPx(c0, c1, c2, xr, sl, lo);
            unitL(c0, c1, c2, LDSA0, 0, sl + 4096, 16, lo, r, g);
            fin = fin3(c0, c1, c2);
          }
          break;
        case 2:
          if (do0) {
            unitPx(c0, c1, c2, xr, slabA + preW[2], lo);
            fin = fin3(c0, c1, c2);
#pragma unroll
            for (int e = 0; e < 4; ++e)
              st2sc(p.xn0, (row0 + g * 4 + e) * H_ + n, tanhf(fin[e]));
          }
          break;
        case 3:
          if (do0) {
            unitL(c0, c1, c2, LDSA0, 0, slabA + preW[3], 16, lo, r, g);
            fin = fin3(c0, c1, c2);
#pragma unroll
            for (int e = 0; e < 4; ++e)
              st2sc(p.hn0, (row0 + g * 4 + e) * H_ + n, tanhf(fin[e]));
          }
          break;
        case 4:
        case 5:
          if (do1) {
            const short* sl = slabA + preW[w];
            unitL(c0, c1, c2, LDSA0, 0, sl, 16, lo, r, g);
            unitL(c0, c1, c2, LDSA1, 0, sl + 16384, 16, lo, r, g);
            fin = fin3(c0, c1, c2);
          }
          break;
        case 6:
          if (do1) {
            unitL(c0, c1, c2, LDSA0, 0, slabA + preW[6], 16, lo, r, g);
            fin = fin3(c0, c1, c2);
#pragma unroll
            for (int e = 0; e < 4; ++e)
              st2sc(p.xn1, (row0 + g * 4 + e) * H_ + n, tanhf(fin[e]));
          }
          break;
        default:
          if (do1) {
            unitL(c0, c1, c2, LDSA1, 0, slabA + preW[7], 16, lo, r, g);
            fin = fin3(c0, c1, c2);
#pragma unroll
            for (int e = 0; e < 4; ++e)
              st2sc(p.hn1, (row0 + g * 4 + e) * H_ + n, tanhf(fin[e]));
          }
          break;
      }
      if ((w == 1 && do0) || (w == 5 && do1)) {
#pragma unroll
        for (int e = 0; e < 4; ++e)
          ldsF[(w == 5 ? 256 : 0) + (g * 4 + e) * 16 + r] = fin[e];
      }
      __syncthreads();
      if (w == 0 && do0) {
        const float bi = p.bhi0[n], bh = p.bhi0[512 + n];
#pragma unroll
        for (int e = 0; e < 4; ++e) {
          float hgv = ldsF[(g * 4 + e) * 16 + r];
          st2sc(p.ch0, (row0 + g * 4 + e) * H_ + n, sigf(fin[e] + bi) * tanhf(hgv + bh));
        }
      }
      if (w == 4 && do1) {
        const float bi = p.bhi1[n], bh = p.bhi1[512 + n];
#pragma unroll
        for (int e = 0; e < 4; ++e) {
          float hgv = ldsF[256 + (g * 4 + e) * 16 + r];
          st2sc(p.ch1, (row0 + g * 4 + e) * H_ + n, sigf(fin[e] + bi) * tanhf(hgv + bh));
        }
      }
      __syncthreads();
    }
    ++bt;
    gbar(p.ctl, bt, grp);

    // ================= phase B ================= (no intra-block redundancy: direct sc1)
    {
      const int L = w >> 2;
      const int tt = w & 3;
      const int ok = L ? do1 : do0;
      f32x4 fA = z;
      if (ok) {
        f32x4 c0 = z, c1 = z, c2 = z;
        const short* slab =
            p.pw + (size_t)s * SLAB_SHORTS + 156 * 1024 + (size_t)L * 49152;
        const short* xn = L ? p.xn1 : p.xn0;
        const short* hn = L ? p.hn1 : p.hn0;
        const short* ch = L ? p.ch1 : p.ch0;
        if (tt == 0)
          unitS(c0, c1, c2, xn + aoff, slab, 16, lo);
        else if (tt == 1)
          unitS(c0, c1, c2, hn + aoff, slab + 16384, 16, lo);
        else if (tt == 2)
          unitS(c0, c1, c2, ch + aoff, slab + 32768, 8, lo);
        else
          unitS(c0, c1, c2, ch + aoff + 256, slab + 40960, 8, lo);
        fA = fin3(c0, c1, c2);
#pragma unroll
        for (int e = 0; e < 4; ++e) ldsF[w * 256 + (g * 4 + e) * 16 + r] = fA[e];
      }
      __syncthreads();
      if ((w == 0 && do0) || (w == 4 && do1)) {
        const float bc = (w == 4 ? p.bcho1 : p.bcho0)[n];
        short* o = w == 4 ? p.o1 : p.o0;
#pragma unroll
        for (int e = 0; e < 4; ++e) {
          const int q = (g * 4 + e) * 16 + r;
          float sum = ldsF[w * 256 + q] + ldsF[(w + 1) * 256 + q] +
                      ldsF[(w + 2) * 256 + q] + ldsF[(w + 3) * 256 + q];
          st2sc(o, (row0 + g * 4 + e) * H_ + n, sigf(sum + bc));
        }
      }
      __syncthreads();
    }
    ++bt;
    gbar(p.ctl, bt, grp);

    // ================= phase C ================= (o staged: 8-way shared)
    {
      const int L = s & 1;
      const int ok = L ? do1 : do0;
      const int u = w >> 1;
      const int h = w & 1;
      const short* o = L ? p.o1 : p.o0;
      if (ok) stageAct(o + row0 * H_, LDSA0);
      __syncthreads();
      if (ok) {
        f32x4 c0 = z, c1 = z, c2 = z;
        const short* slab = p.pw + (size_t)s * SLAB_SHORTS + 252 * 1024 +
                            (size_t)u * 16384 + (size_t)h * 8192;
        unitL(c0, c1, c2, LDSA0, h * 8, slab, 8, lo, r, g);
        f32x4 fin = fin3(c0, c1, c2);
#pragma unroll
        for (int e = 0; e < 4; ++e) ldsF[w * 256 + (g * 4 + e) * 16 + r] = fin[e];
      }
      __syncthreads();
      if ((w == 0 || w == 4) && ok) {
        const int j = (w == 0) ? (s >> 1) : (16 + (s >> 1));
        const int ub = (w == 0) ? 0 : 4;
        const short* xn = L ? p.xn1 : p.xn0;
        const short* hn = L ? p.hn1 : p.hn0;
        const short* ch = L ? p.ch1 : p.ch0;
        short* hs = L ? p.h1s : p.h0s;
        unsigned int dx[8], dh[8], dc[8];
#pragma unroll
        for (int e = 0; e < 4; ++e) {
          const int idx = (row0 + g * 4 + e) * H_ + j * 16 + r;
          dx[e * 2] = ldus(xn + idx);
          dx[e * 2 + 1] = ldus(xn + idx + APLANE);
          dh[e * 2] = ldus(hn + idx);
          dh[e * 2 + 1] = ldus(hn + idx + APLANE);
          dc[e * 2] = ldus(ch + idx);
          dc[e * 2 + 1] = ldus(ch + idx + APLANE);
        }
        VMDRAIN();
#pragma unroll
        for (int e = 0; e < 4; ++e) {
          const int q = (g * 4 + e) * 16 + r;
          const float av = ldsF[(ub + 0) * 256 + q] + ldsF[(ub + 1) * 256 + q];
          const float bv = ldsF[(ub + 2) * 256 + q] + ldsF[(ub + 3) * 256 + q];
          const float xv = h2f(dx[e * 2]) + h2f(dx[e * 2 + 1]) * SC1F;
          const float hv = h2f(dh[e * 2]) + h2f(dh[e * 2 + 1]) * SC1F;
          const float cv = h2f(dc[e * 2]) + h2f(dc[e * 2 + 1]) * SC1F;
          const int idx = (row0 + g * 4 + e) * H_ + j * 16 + r;
          const float hval = av * xv + bv * hv + (1.f - av - bv) * cv;
          st2sc(hs, idx, hval);
          if (L) p.out[(size_t)(i - 1) * B_ * H_ + idx] = hval;
        }
      }
      __syncthreads();
    }
    ++bt;
    gbar(p.ctl, bt, grp);
  }
}

// ---------------- prologue: repack (r11-validated mapping) ----------------
struct WP18 {
  const float* m[18];
};
__global__ void repack(WP18 wp, short* pw) {
  const long long t8 = (long long)blockIdx.x * 256 + threadIdx.x;
  const long long id = t8 * 8;
  if (id >= (long long)PK_TOT) return;
  const int s = (int)(id / SLAB_SHORTS);
  const int rem = (int)(id % SLAB_SHORTS);
  const int c = rem >> 10;
  const int r2 = rem & 1023;
  const int p = r2 >> 9;
  const int q2 = r2 & 511;
  const int rr = q2 >> 5;
  const int gg = (q2 & 31) >> 3;
  const int n0 = s * 16;
  int mat, row, kb;
  if (c < 156) {
    const int segA[9] = {0, 20, 40, 44, 60, 92, 124, 140, 156};
    int sg = 0;
    while (c >= segA[sg + 1]) ++sg;
    const int cl = c - segA[sg];
    const int kin = cl * 32 + gg * 8;
    switch (sg) {
      case 0:
        row = n0 + rr;
        if (kin < 128) { mat = 0; kb = kin; } else { mat = 1; kb = kin - 128; }
        break;
      case 1:
        row = 512 + n0 + rr;
        if (kin < 128) { mat = 0; kb = kin; } else { mat = 1; kb = kin - 128; }
        break;
      case 2: mat = 2; row = n0 + rr; kb = kin; break;
      case 3: mat = 3; row = n0 + rr; kb = kin; break;
      case 4:
        row = n0 + rr;
        if (kin < 512) { mat = 9; kb = kin; } else { mat = 10; kb = kin - 512; }
        break;
      case 5:
        row = 512 + n0 + rr;
        if (kin < 512) { mat = 9; kb = kin; } else { mat = 10; kb = kin - 512; }
        break;
      case 6: mat = 11; row = n0 + rr; kb = kin; break;
      default: mat = 12; row = n0 + rr; kb = kin; break;
    }
  } else if (c < 252) {
    const int cl = c - 156;
    const int L = cl >= 48;
    const int cc = cl - (L ? 48 : 0);
    mat = (L ? 13 : 4) + (cc >> 4);
    row = n0 + rr;
    kb = (cc & 15) * 32 + gg * 8;
  } else {
    const int cc = c - 252;
    const int u = cc >> 4;
    const int L = s & 1;
    const int j = (u < 2) ? (s >> 1) : (16 + (s >> 1));
    mat = (L ? 16 : 7) + (u & 1);
    row = j * 16 + rr;
    kb = (cc & 15) * 32 + gg * 8;
  }
  const int KS = (mat == 0 || mat == 2) ? 128 : 512;
  const float* src = wp.m[mat] + (long long)row * KS + kb;
  bf16x8 o8;
#pragma unroll
  for (int e = 0; e < 8; ++e) {
    float v = src[e];
    _Float16 h0 = (_Float16)v;
    short sv;
    if (p == 0)
      sv = __builtin_bit_cast(short, h0);
    else {
      _Float16 h1 = (_Float16)((v - (float)h0) * 2048.0f);
      sv = __builtin_bit_cast(short, h1);
    }
    o8[e] = sv;
  }
  *(bf16x8*)(pw + id) = o8;
}

// ---------------- final: in-place sinrelu + LayerNorm over H on d_out ----------------
__global__ void eltm_kLN(float* __restrict__ out, const float* __restrict__ g,
                         const float* __restrict__ bta) {
  const int row = blockIdx.x * 4 + (threadIdx.x >> 6);
  const int lane = threadIdx.x & 63;
  float* r = out + (size_t)row * H_;
  float v[8];
  float s = 0.f, s2 = 0.f;
#pragma unroll
  for (int i = 0; i < 8; ++i) {
    float x = r[lane + i * 64];
    float sv = (x >= 0.f) ? (x + sinf(x)) : 0.f;
    v[i] = sv;
    s += sv;
    s2 += sv * sv;
  }
#pragma unroll
  for (int m = 1; m < 64; m <<= 1) {
    s += __shfl_xor(s, m);
    s2 += __shfl_xor(s2, m);
  }
  const float mean = s * (1.f / 512.f);
  const float var = s2 * (1.f / 512.f) - mean * mean;
  const float rstd = rsqrtf(var + 1e-5f);
#pragma unroll
  for (int i = 0; i < 8; ++i) {
    const int c = lane + i * 64;
    r[c] = (v[i] - mean) * rstd * g[c] + bta[c];
  }
}

extern "C" void kernel_launch(void* const* d_in, const int* in_sizes, int n_in,
                              void* d_out, int out_size, void* d_ws, size_t ws_size,
                              hipStream_t stream) {
#define W(i) ((const float*)d_in[i])
  short* pw = (short*)d_ws;
  short* acts = pw + (size_t)PK_TOT;
  short* h0s = acts;
  short* h1s = acts + ASZ;
  short* xn0 = acts + 2 * ASZ;
  short* hn0 = acts + 3 * ASZ;
  short* ch0 = acts + 4 * ASZ;
  short* xn1 = acts + 5 * ASZ;
  short* hn1 = acts + 6 * ASZ;
  short* ch1 = acts + 7 * ASZ;
  short* o0 = acts + 8 * ASZ;
  short* o1 = acts + 9 * ASZ;
  unsigned int* ctl = (unsigned int*)(acts + 10 * (size_t)ASZ);
  float* out = (float*)d_out;

  WP18 wps;
  const int srcIdx[18] = {1,  2,  4,  5,  6,  7,  8,  10, 11,
                          12, 13, 15, 16, 17, 18, 19, 21, 22};
  for (int i = 0; i < 18; ++i) wps.m[i] = W(srcIdx[i]);

  repack<<<PK_TOT / 8 / 256, 256, 0, stream>>>(wps, pw);
  hipMemsetAsync(h0s, 0, (size_t)2 * ASZ * sizeof(short), stream);
  hipMemsetAsync(ctl, 0, 4096, stream);

  hipFuncSetAttribute((const void*)eltm_p, hipFuncAttributeMaxDynamicSharedMemorySize,
                      LDSTOT);
  PP pa;
  pa.x = (const float*)d_in[0];
  pa.pw = pw;
  pa.h0s = h0s;
  pa.h1s = h1s;
  pa.xn0 = xn0;
  pa.hn0 = hn0;
  pa.ch0 = ch0;
  pa.xn1 = xn1;
  pa.hn1 = hn1;
  pa.ch1 = ch1;
  pa.o0 = o0;
  pa.o1 = o1;
  pa.bhi0 = W(3);
  pa.bcho0 = W(9);
  pa.bhi1 = W(14);
  pa.bcho1 = W(20);
  pa.out = out;
  pa.ctl = ctl;
  eltm_p<<<NB_, 512, LDSTOT, stream>>>(pa);

  eltm_kLN<<<16384, 256, 0, stream>>>(out, W(23), W(24));
#undef W
}

// Round 13
// 31204.483 us; speedup vs baseline: 3.0469x; 1.0429x over previous
//
#include <hip/hip_runtime.h>
#include <hip/hip_bf16.h>

#define S_ 512
#define B_ 128
#define D_ 128
#define H_ 512
#define NB_ 256

// ---- packed f16 2-plane weight layout: 32 slabs x 316 chunks x 1024 shorts ----
#define SLAB_SHORTS 323584
#define PK_TOT 10354688
#define APLANE 65536
#define ASZ    131072  // 2*APLANE

#define SC1F 4.8828125e-4f          // 2^-11
#define SC2F 2.384185791015625e-7f  // 2^-22

// LDS map (bytes): ldsF scratch 0..8191; stage slots: LDSB + t*32768 (t=0,1,2)
#define LDSB 8192
#define LDSTOT 106496

typedef short bf16x8 __attribute__((ext_vector_type(8)));
typedef _Float16 f16x8 __attribute__((ext_vector_type(8)));
typedef int i32x4 __attribute__((ext_vector_type(4)));
typedef float f32x4 __attribute__((ext_vector_type(4)));

__device__ __forceinline__ float sigf(float x) { return 1.0f / (1.0f + expf(-x)); }

// plain cached 16B load (weights/x only — L2-resident, never invalidated)
__device__ __forceinline__ i32x4 ldg(const short* p) {
  i32x4 o;
  asm volatile("global_load_dwordx4 %0, %1, off" : "=v"(o) : "v"(p));
  return o;
}
// sc1 coherent 16B load (activations — reads MALL truth)
__device__ __forceinline__ i32x4 ldgs(const short* p) {
  i32x4 o;
  asm volatile("global_load_dwordx4 %0, %1, off sc1" : "=v"(o) : "v"(p));
  return o;
}
__device__ __forceinline__ unsigned int ldus(const short* p) {
  unsigned int o;
  asm volatile("global_load_ushort %0, %1, off sc1" : "=v"(o) : "v"(p));
  return o;
}
#define VMDRAIN()                                    \
  do {                                               \
    asm volatile("s_waitcnt vmcnt(0)" ::: "memory"); \
    __builtin_amdgcn_sched_barrier(0);               \
  } while (0)

// sc1 write-through store (agent-visible after vmcnt(0); no dirty L2 line)
__device__ __forceinline__ void stg16s(short* p, unsigned int v) {
  asm volatile("global_store_short %0, %1, off sc1" ::"v"(p), "v"(v) : "memory");
}
__device__ __forceinline__ void st2sc(short* buf, int idx, float v) {
  _Float16 h0 = (_Float16)v;
  _Float16 h1 = (_Float16)((v - (float)h0) * 2048.0f);
  stg16s(buf + idx, (unsigned int)__builtin_bit_cast(unsigned short, h0));
  stg16s(buf + idx + APLANE, (unsigned int)__builtin_bit_cast(unsigned short, h1));
}
__device__ __forceinline__ float h2f(unsigned int u) {
  return (float)__builtin_bit_cast(_Float16, (unsigned short)(u & 0xffffu));
}

#define MFMAH(a, b, c) __builtin_amdgcn_mfma_f32_16x16x32_f16(a, b, c, 0, 0, 0)
#define BC16(x) __builtin_bit_cast(f16x8, x)

__device__ __forceinline__ void mac4(f32x4& c0, f32x4& c1, f32x4& c2, const f16x8& a0,
                                     const f16x8& a1, const f16x8& w0, const f16x8& w1) {
  c0 = MFMAH(a0, w0, c0);
  c1 = MFMAH(a0, w1, c1);
  c1 = MFMAH(a1, w0, c1);
  c2 = MFMAH(a1, w1, c2);
}
__device__ __forceinline__ f32x4 fin3(const f32x4& c0, const f32x4& c1,
                                      const f32x4& c2) {
  f32x4 o;
#pragma unroll
  for (int e = 0; e < 4; ++e) o[e] = c0[e] + SC1F * c1[e] + SC2F * c2[e];
  return o;
}

// cooperative stage: one 16-row x 512-k 2-plane slice -> LDS slot (swizzled), 4/thread
__device__ __forceinline__ void stageAct(const short* src, int ldsBase) {
  extern __shared__ char smem[];
  i32x4 v[4];
  int ad[4];
#pragma unroll
  for (int t = 0; t < 4; ++t) {
    const int c = (int)threadIdx.x + t * 512;
    const int pl = c >> 10;
    const int u = c & 1023;
    const int rr = u >> 6;
    const int k16 = u & 63;
    v[t] = ldgs(src + pl * APLANE + rr * H_ + k16 * 8);
    ad[t] = ldsBase + pl * 16384 + ((rr * 1024 + k16 * 16) ^ ((rr & 7) << 4));
  }
  VMDRAIN();
#pragma unroll
  for (int t = 0; t < 4; ++t) *(i32x4*)(smem + ad[t]) = v[t];
}

// stage TWO slices with a single drain (slots 0,1)
__device__ __forceinline__ void stage2(const short* t0, const short* t1) {
  extern __shared__ char smem[];
  i32x4 v[8];
  int ad[8];
#pragma unroll
  for (int tt = 0; tt < 2; ++tt)
#pragma unroll
    for (int t = 0; t < 4; ++t) {
      const int idx = tt * 4 + t;
      const int c = (int)threadIdx.x + t * 512;
      const int pl = c >> 10;
      const int u = c & 1023;
      const int rr = u >> 6;
      const int k16 = u & 63;
      const short* src = tt ? t1 : t0;
      v[idx] = ldgs(src + pl * APLANE + rr * H_ + k16 * 8);
      ad[idx] = LDSB + tt * 32768 + pl * 16384 +
                ((rr * 1024 + k16 * 16) ^ ((rr & 7) << 4));
    }
  VMDRAIN();
#pragma unroll
  for (int idx = 0; idx < 8; ++idx) *(i32x4*)(smem + ad[idx]) = v[idx];
}

// stage THREE slices with a single drain (slots 0,1,2) — phase B
__device__ __forceinline__ void stage3(const short* t0, const short* t1,
                                       const short* t2) {
  extern __shared__ char smem[];
  i32x4 v[12];
  int ad[12];
#pragma unroll
  for (int tt = 0; tt < 3; ++tt)
#pragma unroll
    for (int t = 0; t < 4; ++t) {
      const int idx = tt * 4 + t;
      const int c = (int)threadIdx.x + t * 512;
      const int pl = c >> 10;
      const int u = c & 1023;
      const int rr = u >> 6;
      const int k16 = u & 63;
      const short* src = (tt == 0) ? t0 : ((tt == 1) ? t1 : t2);
      v[idx] = ldgs(src + pl * APLANE + rr * H_ + k16 * 8);
      ad[idx] = LDSB + tt * 32768 + pl * 16384 +
                ((rr * 1024 + k16 * 16) ^ ((rr & 7) << 4));
    }
  VMDRAIN();
#pragma unroll
  for (int idx = 0; idx < 12; ++idx) *(i32x4*)(smem + ad[idx]) = v[idx];
}

// GEMV unit: A from LDS slot (staged, swizzled), W plain global (L2-hot).
__device__ __forceinline__ void unitL(f32x4& c0, f32x4& c1, f32x4& c2, int ldsBase,
                                      int qoff, const short* slabW, int nks, int lo,
                                      int r, int g) {
  extern __shared__ char smem[];
  for (int q = 0; q < nks; q += 4) {
    i32x4 W0[4], W1[4];
#pragma unroll
    for (int u = 0; u < 4; ++u) {
      const short* wp = slabW + (size_t)(q + u) * 1024 + lo;
      W0[u] = ldg(wp);
      W1[u] = ldg(wp + 512);
    }
    bf16x8 A0[4], A1[4];
#pragma unroll
    for (int u = 0; u < 4; ++u) {
      const int ka = ((r * 1024 + (q + qoff + u) * 64 + g * 16) ^ ((r & 7) << 4));
      A0[u] = *(const bf16x8*)(smem + ldsBase + ka);
      A1[u] = *(const bf16x8*)(smem + ldsBase + 16384 + ka);
    }
    VMDRAIN();
#pragma unroll
    for (int u = 0; u < 4; ++u)
      mac4(c0, c1, c2, BC16(A0[u]), BC16(A1[u]), BC16(W0[u]), BC16(W1[u]));
  }
}

// phase-B compute: wave handles 6 chunk-units c=cbase..cbase+5 of [t(0..2)|q(0..15)];
// weight chunk index == c in the B slab; A from staged LDS slot t.
__device__ __forceinline__ void computeB(f32x4& c0, f32x4& c1, f32x4& c2, int cbase,
                                         const short* slabB, int lo, int r, int g) {
  extern __shared__ char smem[];
  i32x4 W0[6], W1[6];
#pragma unroll
  for (int u = 0; u < 6; ++u) {
    const short* wp = slabB + (size_t)(cbase + u) * 1024 + lo;
    W0[u] = ldg(wp);
    W1[u] = ldg(wp + 512);
  }
  bf16x8 A0[6], A1[6];
#pragma unroll
  for (int u = 0; u < 6; ++u) {
    const int c = cbase + u;
    const int t = c >> 4;
    const int q = c & 15;
    const int ka =
        LDSB + t * 32768 + ((r * 1024 + q * 64 + g * 16) ^ ((r & 7) << 4));
    A0[u] = *(const bf16x8*)(smem + ka);
    A1[u] = *(const bf16x8*)(smem + ka + 16384);
  }
  VMDRAIN();
#pragma unroll
  for (int u = 0; u < 6; ++u)
    mac4(c0, c1, c2, BC16(A0[u]), BC16(A1[u]), BC16(W0[u]), BC16(W1[u]));
}

// x-part (4 kchunks of fp32 x, plain cached, split on the fly)
__device__ __forceinline__ void unitPx(f32x4& c0, f32x4& c1, f32x4& c2,
                                       const float* xRow, const short* slab, int lo) {
  i32x4 W0[4], W1[4];
  f16x8 A0[4], A1[4];
#pragma unroll
  for (int u = 0; u < 4; ++u) {
    const short* wp = slab + (size_t)u * 1024 + lo;
    W0[u] = ldg(wp);
    W1[u] = ldg(wp + 512);
#pragma unroll
    for (int e = 0; e < 8; ++e) {
      float v = xRow[u * 32 + e];
      _Float16 h0 = (_Float16)v;
      A0[u][e] = h0;
      A1[u][e] = (_Float16)((v - (float)h0) * 2048.0f);
    }
  }
  VMDRAIN();
#pragma unroll
  for (int u = 0; u < 4; ++u) mac4(c0, c1, c2, A0[u], A1[u], BC16(W0[u]), BC16(W1[u]));
}

// ---- atomics (agent scope, relaxed, monotonic) ----
__device__ __forceinline__ unsigned int afa(unsigned int* p) {
  return __hip_atomic_fetch_add(p, 1u, __ATOMIC_RELAXED, __HIP_MEMORY_SCOPE_AGENT);
}
__device__ __forceinline__ unsigned int ald(const unsigned int* p) {
  return __hip_atomic_load(p, __ATOMIC_RELAXED, __HIP_MEMORY_SCOPE_AGENT);
}

// global grouped barrier; L1-only invalidate (weights in L2 stay resident).
__device__ __forceinline__ void gbar(unsigned int* ctl, unsigned int t, int grp) {
  asm volatile("s_waitcnt vmcnt(0) lgkmcnt(0)" ::: "memory");  // release sc1 stores
  __syncthreads();
  if (threadIdx.x == 0) {
    unsigned int a = afa(&ctl[grp * 32]);
    if (a == t * 32u - 1u) {
      unsigned int m = afa(&ctl[256]);
      if (m == t * 8u - 1u)
        __hip_atomic_store(&ctl[288], t, __ATOMIC_RELAXED, __HIP_MEMORY_SCOPE_AGENT);
    }
    int guard = 0;
    while (ald(&ctl[288]) < t) {
      __builtin_amdgcn_s_sleep(2);
      if (++guard > (1 << 24)) break;  // bail: wrong answer beats hang
    }
  }
  __syncthreads();
  asm volatile("buffer_inv sc0" ::: "memory");  // L1 only
  __builtin_amdgcn_sched_barrier(0);
}

struct PP {
  const float* x;
  const short* pw;
  short* h0s;
  short* h1s;
  short* xn0;
  short* hn0;
  short* ch0;
  short* xn1;
  short* hn1;
  short* ch1;
  short* o0;
  short* o1;
  const float* bhi0;
  const float* bcho0;
  const float* bhi1;
  const float* bcho1;
  float* out;
  unsigned int* ctl;
};

// Deterministic bijective 2-D partition: s = (bid&7)*4 + (bid>>6), row0 = ((bid>>3)&7)*16
__global__ __launch_bounds__(512, 1) void eltm_p(PP p) {
  extern __shared__ char smem[];
  float* ldsF = (float*)smem;
  const int tid = threadIdx.x;
  const int lane = tid & 63;
  const int w = tid >> 6;
  const int r = lane & 15;
  const int g = lane >> 4;
  const int lo = r * 32 + g * 8;
  const f32x4 z = {0.f, 0.f, 0.f, 0.f};

  const int bid = blockIdx.x;
  const int s = (bid & 7) * 4 + (bid >> 6);
  const int row0 = ((bid >> 3) & 7) * 16;
  const int grp = bid & 7;

  const int n = s * 16 + r;
  static const int preW[8] = {0, 20480, 40960, 45056, 61440, 94208, 126976, 143360};

  unsigned int bt = 0;
  for (int i = 0; i <= S_; ++i) {
    const int do0 = i < S_;
    const int do1 = i >= 1;
    const float* xr = p.x + ((size_t)i * B_ + row0 + r) * D_ + g * 8;
    const short* slabA = p.pw + (size_t)s * SLAB_SHORTS;

    // ================= phase A ================= (h0s slot 0, h1s slot 1)
    {
      if (do1)
        stage2(p.h0s + row0 * H_, p.h1s + row0 * H_);
      else
        stageAct(p.h0s + row0 * H_, LDSB);
      __syncthreads();
      f32x4 c0 = z, c1 = z, c2 = z;
      f32x4 fin = z;
      switch (w) {
        case 0:
        case 1:
          if (do0) {
            const short* sl = slabA + preW[w];
            unitPx(c0, c1, c2, xr, sl, lo);
            unitL(c0, c1, c2, LDSB, 0, sl + 4096, 16, lo, r, g);
            fin = fin3(c0, c1, c2);
          }
          break;
        case 2:
          if (do0) {
            unitPx(c0, c1, c2, xr, slabA + preW[2], lo);
            fin = fin3(c0, c1, c2);
#pragma unroll
            for (int e = 0; e < 4; ++e)
              st2sc(p.xn0, (row0 + g * 4 + e) * H_ + n, tanhf(fin[e]));
          }
          break;
        case 3:
          if (do0) {
            unitL(c0, c1, c2, LDSB, 0, slabA + preW[3], 16, lo, r, g);
            fin = fin3(c0, c1, c2);
#pragma unroll
            for (int e = 0; e < 4; ++e)
              st2sc(p.hn0, (row0 + g * 4 + e) * H_ + n, tanhf(fin[e]));
          }
          break;
        case 4:
        case 5:
          if (do1) {
            const short* sl = slabA + preW[w];
            unitL(c0, c1, c2, LDSB, 0, sl, 16, lo, r, g);
            unitL(c0, c1, c2, LDSB + 32768, 0, sl + 16384, 16, lo, r, g);
            fin = fin3(c0, c1, c2);
          }
          break;
        case 6:
          if (do1) {
            unitL(c0, c1, c2, LDSB, 0, slabA + preW[6], 16, lo, r, g);
            fin = fin3(c0, c1, c2);
#pragma unroll
            for (int e = 0; e < 4; ++e)
              st2sc(p.xn1, (row0 + g * 4 + e) * H_ + n, tanhf(fin[e]));
          }
          break;
        default:
          if (do1) {
            unitL(c0, c1, c2, LDSB + 32768, 0, slabA + preW[7], 16, lo, r, g);
            fin = fin3(c0, c1, c2);
#pragma unroll
            for (int e = 0; e < 4; ++e)
              st2sc(p.hn1, (row0 + g * 4 + e) * H_ + n, tanhf(fin[e]));
          }
          break;
      }
      if ((w == 1 && do0) || (w == 5 && do1)) {
#pragma unroll
        for (int e = 0; e < 4; ++e)
          ldsF[(w == 5 ? 256 : 0) + (g * 4 + e) * 16 + r] = fin[e];
      }
      __syncthreads();
      if (w == 0 && do0) {
        const float bi = p.bhi0[n], bh = p.bhi0[512 + n];
#pragma unroll
        for (int e = 0; e < 4; ++e) {
          float hgv = ldsF[(g * 4 + e) * 16 + r];
          st2sc(p.ch0, (row0 + g * 4 + e) * H_ + n, sigf(fin[e] + bi) * tanhf(hgv + bh));
        }
      }
      if (w == 4 && do1) {
        const float bi = p.bhi1[n], bh = p.bhi1[512 + n];
#pragma unroll
        for (int e = 0; e < 4; ++e) {
          float hgv = ldsF[256 + (g * 4 + e) * 16 + r];
          st2sc(p.ch1, (row0 + g * 4 + e) * H_ + n, sigf(fin[e] + bi) * tanhf(hgv + bh));
        }
      }
      __syncthreads();
    }
    ++bt;
    gbar(p.ctl, bt, grp);

    // ================= phase B ================= (staged; 8 waves x 6 chunk-units)
    {
      const short* slabB = p.pw + (size_t)s * SLAB_SHORTS + 156 * 1024;
      // ---- L0 ----
      if (do0) stage3(p.xn0 + row0 * H_, p.hn0 + row0 * H_, p.ch0 + row0 * H_);
      __syncthreads();
      if (do0) {
        f32x4 c0 = z, c1 = z, c2 = z;
        computeB(c0, c1, c2, w * 6, slabB, lo, r, g);
        f32x4 fA = fin3(c0, c1, c2);
#pragma unroll
        for (int e = 0; e < 4; ++e) ldsF[w * 256 + (g * 4 + e) * 16 + r] = fA[e];
      }
      __syncthreads();
      if (w == 0 && do0) {
        const float bc = p.bcho0[n];
#pragma unroll
        for (int e = 0; e < 4; ++e) {
          const int q = (g * 4 + e) * 16 + r;
          float sum = 0.f;
#pragma unroll
          for (int ww = 0; ww < 8; ++ww) sum += ldsF[ww * 256 + q];
          st2sc(p.o0, (row0 + g * 4 + e) * H_ + n, sigf(sum + bc));
        }
      }
      // ---- L1 ---- (stage overwrites LDSB; ldsF reads by w0 happen concurrently, disjoint)
      if (do1) stage3(p.xn1 + row0 * H_, p.hn1 + row0 * H_, p.ch1 + row0 * H_);
      __syncthreads();
      if (do1) {
        f32x4 c0 = z, c1 = z, c2 = z;
        computeB(c0, c1, c2, w * 6, slabB + 49152, lo, r, g);
        f32x4 fA = fin3(c0, c1, c2);
#pragma unroll
        for (int e = 0; e < 4; ++e) ldsF[w * 256 + (g * 4 + e) * 16 + r] = fA[e];
      }
      __syncthreads();
      if (w == 0 && do1) {
        const float bc = p.bcho1[n];
#pragma unroll
        for (int e = 0; e < 4; ++e) {
          const int q = (g * 4 + e) * 16 + r;
          float sum = 0.f;
#pragma unroll
          for (int ww = 0; ww < 8; ++ww) sum += ldsF[ww * 256 + q];
          st2sc(p.o1, (row0 + g * 4 + e) * H_ + n, sigf(sum + bc));
        }
      }
      __syncthreads();
    }
    ++bt;
    gbar(p.ctl, bt, grp);

    // ================= phase C ================= (o staged into slot 0)
    {
      const int L = s & 1;
      const int ok = L ? do1 : do0;
      const int u = w >> 1;
      const int h = w & 1;
      const short* o = L ? p.o1 : p.o0;
      if (ok) stageAct(o + row0 * H_, LDSB);
      __syncthreads();
      if (ok) {
        f32x4 c0 = z, c1 = z, c2 = z;
        const short* slab = p.pw + (size_t)s * SLAB_SHORTS + 252 * 1024 +
                            (size_t)u * 16384 + (size_t)h * 8192;
        unitL(c0, c1, c2, LDSB, h * 8, slab, 8, lo, r, g);
        f32x4 fin = fin3(c0, c1, c2);
#pragma unroll
        for (int e = 0; e < 4; ++e) ldsF[w * 256 + (g * 4 + e) * 16 + r] = fin[e];
      }
      __syncthreads();
      if ((w == 0 || w == 4) && ok) {
        const int j = (w == 0) ? (s >> 1) : (16 + (s >> 1));
        const int ub = (w == 0) ? 0 : 4;
        const short* xn = L ? p.xn1 : p.xn0;
        const short* hn = L ? p.hn1 : p.hn0;
        const short* ch = L ? p.ch1 : p.ch0;
        short* hs = L ? p.h1s : p.h0s;
        unsigned int dx[8], dh[8], dc[8];
#pragma unroll
        for (int e = 0; e < 4; ++e) {
          const int idx = (row0 + g * 4 + e) * H_ + j * 16 + r;
          dx[e * 2] = ldus(xn + idx);
          dx[e * 2 + 1] = ldus(xn + idx + APLANE);
          dh[e * 2] = ldus(hn + idx);
          dh[e * 2 + 1] = ldus(hn + idx + APLANE);
          dc[e * 2] = ldus(ch + idx);
          dc[e * 2 + 1] = ldus(ch + idx + APLANE);
        }
        VMDRAIN();
#pragma unroll
        for (int e = 0; e < 4; ++e) {
          const int q = (g * 4 + e) * 16 + r;
          const float av = ldsF[(ub + 0) * 256 + q] + ldsF[(ub + 1) * 256 + q];
          const float bv = ldsF[(ub + 2) * 256 + q] + ldsF[(ub + 3) * 256 + q];
          const float xv = h2f(dx[e * 2]) + h2f(dx[e * 2 + 1]) * SC1F;
          const float hv = h2f(dh[e * 2]) + h2f(dh[e * 2 + 1]) * SC1F;
          const float cv = h2f(dc[e * 2]) + h2f(dc[e * 2 + 1]) * SC1F;
          const int idx = (row0 + g * 4 + e) * H_ + j * 16 + r;
          const float hval = av * xv + bv * hv + (1.f - av - bv) * cv;
          st2sc(hs, idx, hval);
          if (L) p.out[(size_t)(i - 1) * B_ * H_ + idx] = hval;
        }
      }
      __syncthreads();
    }
    ++bt;
    gbar(p.ctl, bt, grp);
  }
}

// ---------------- prologue: repack (r11-validated mapping) ----------------
struct WP18 {
  const float* m[18];
};
__global__ void repack(WP18 wp, short* pw) {
  const long long t8 = (long long)blockIdx.x * 256 + threadIdx.x;
  const long long id = t8 * 8;
  if (id >= (long long)PK_TOT) return;
  const int s = (int)(id / SLAB_SHORTS);
  const int rem = (int)(id % SLAB_SHORTS);
  const int c = rem >> 10;
  const int r2 = rem & 1023;
  const int p = r2 >> 9;
  const int q2 = r2 & 511;
  const int rr = q2 >> 5;
  const int gg = (q2 & 31) >> 3;
  const int n0 = s * 16;
  int mat, row, kb;
  if (c < 156) {
    const int segA[9] = {0, 20, 40, 44, 60, 92, 124, 140, 156};
    int sg = 0;
    while (c >= segA[sg + 1]) ++sg;
    const int cl = c - segA[sg];
    const int kin = cl * 32 + gg * 8;
    switch (sg) {
      case 0:
        row = n0 + rr;
        if (kin < 128) { mat = 0; kb = kin; } else { mat = 1; kb = kin - 128; }
        break;
      case 1:
        row = 512 + n0 + rr;
        if (kin < 128) { mat = 0; kb = kin; } else { mat = 1; kb = kin - 128; }
        break;
      case 2: mat = 2; row = n0 + rr; kb = kin; break;
      case 3: mat = 3; row = n0 + rr; kb = kin; break;
      case 4:
        row = n0 + rr;
        if (kin < 512) { mat = 9; kb = kin; } else { mat = 10; kb = kin - 512; }
        break;
      case 5:
        row = 512 + n0 + rr;
        if (kin < 512) { mat = 9; kb = kin; } else { mat = 10; kb = kin - 512; }
        break;
      case 6: mat = 11; row = n0 + rr; kb = kin; break;
      default: mat = 12; row = n0 + rr; kb = kin; break;
    }
  } else if (c < 252) {
    const int cl = c - 156;
    const int L = cl >= 48;
    const int cc = cl - (L ? 48 : 0);
    mat = (L ? 13 : 4) + (cc >> 4);
    row = n0 + rr;
    kb = (cc & 15) * 32 + gg * 8;
  } else {
    const int cc = c - 252;
    const int u = cc >> 4;
    const int L = s & 1;
    const int j = (u < 2) ? (s >> 1) : (16 + (s >> 1));
    mat = (L ? 16 : 7) + (u & 1);
    row = j * 16 + rr;
    kb = (cc & 15) * 32 + gg * 8;
  }
  const int KS = (mat == 0 || mat == 2) ? 128 : 512;
  const float* src = wp.m[mat] + (long long)row * KS + kb;
  bf16x8 o8;
#pragma unroll
  for (int e = 0; e < 8; ++e) {
    float v = src[e];
    _Float16 h0 = (_Float16)v;
    short sv;
    if (p == 0)
      sv = __builtin_bit_cast(short, h0);
    else {
      _Float16 h1 = (_Float16)((v - (float)h0) * 2048.0f);
      sv = __builtin_bit_cast(short, h1);
    }
    o8[e] = sv;
  }
  *(bf16x8*)(pw + id) = o8;
}

// ---------------- final: in-place sinrelu + LayerNorm over H on d_out ----------------
__global__ void eltm_kLN(float* __restrict__ out, const float* __restrict__ g,
                         const float* __restrict__ bta) {
  const int row = blockIdx.x * 4 + (threadIdx.x >> 6);
  const int lane = threadIdx.x & 63;
  float* r = out + (size_t)row * H_;
  float v[8];
  float s = 0.f, s2 = 0.f;
#pragma unroll
  for (int i = 0; i < 8; ++i) {
    float x = r[lane + i * 64];
    float sv = (x >= 0.f) ? (x + sinf(x)) : 0.f;
    v[i] = sv;
    s += sv;
    s2 += sv * sv;
  }
#pragma unroll
  for (int m = 1; m < 64; m <<= 1) {
    s += __shfl_xor(s, m);
    s2 += __shfl_xor(s2, m);
  }
  const float mean = s * (1.f / 512.f);
  const float var = s2 * (1.f / 512.f) - mean * mean;
  const float rstd = rsqrtf(var + 1e-5f);
#pragma unroll
  for (int i = 0; i < 8; ++i) {
    const int c = lane + i * 64;
    r[c] = (v[i] - mean) * rstd * g[c] + bta[c];
  }
}

extern "C" void kernel_launch(void* const* d_in, const int* in_sizes, int n_in,
                              void* d_out, int out_size, void* d_ws, size_t ws_size,
                              hipStream_t stream) {
#define W(i) ((const float*)d_in[i])
  short* pw = (short*)d_ws;
  short* acts = pw + (size_t)PK_TOT;
  short* h0s = acts;
  short* h1s = acts + ASZ;
  short* xn0 = acts + 2 * ASZ;
  short* hn0 = acts + 3 * ASZ;
  short* ch0 = acts + 4 * ASZ;
  short* xn1 = acts + 5 * ASZ;
  short* hn1 = acts + 6 * ASZ;
  short* ch1 = acts + 7 * ASZ;
  short* o0 = acts + 8 * ASZ;
  short* o1 = acts + 9 * ASZ;
  unsigned int* ctl = (unsigned int*)(acts + 10 * (size_t)ASZ);
  float* out = (float*)d_out;

  WP18 wps;
  const int srcIdx[18] = {1,  2,  4,  5,  6,  7,  8,  10, 11,
                          12, 13, 15, 16, 17, 18, 19, 21, 22};
  for (int i = 0; i < 18; ++i) wps.m[i] = W(srcIdx[i]);

  repack<<<PK_TOT / 8 / 256, 256, 0, stream>>>(wps, pw);
  hipMemsetAsync(h0s, 0, (size_t)2 * ASZ * sizeof(short), stream);
  hipMemsetAsync(ctl, 0, 4096, stream);

  hipFuncSetAttribute((const void*)eltm_p, hipFuncAttributeMaxDynamicSharedMemorySize,
                      LDSTOT);
  PP pa;
  pa.x = (const float*)d_in[0];
  pa.pw = pw;
  pa.h0s = h0s;
  pa.h1s = h1s;
  pa.xn0 = xn0;
  pa.hn0 = hn0;
  pa.ch0 = ch0;
  pa.xn1 = xn1;
  pa.hn1 = hn1;
  pa.ch1 = ch1;
  pa.o0 = o0;
  pa.o1 = o1;
  pa.bhi0 = W(3);
  pa.bcho0 = W(9);
  pa.bhi1 = W(14);
  pa.bcho1 = W(20);
  pa.out = out;
  pa.ctl = ctl;
  eltm_p<<<NB_, 512, LDSTOT, stream>>>(pa);

  eltm_kLN<<<16384, 256, 0, stream>>>(out, W(23), W(24));
#undef W
}